// Round 8
// baseline (14604.547 us; speedup 1.0000x reference)
//
#include <hip/hip_runtime.h>
#include <hip/hip_fp16.h>
#include <math.h>

// Persistent RK45 (Dormand-Prince, FSAL) integrator for
//   dy/dt = y * (r + A@y + eps@P[d(t)]),  n=4096, up to 512 adaptive steps.
// R15 = R14 with stages 1-6 switched to TAGGED 2-leg exchanges.
//   R14 (12.37ms, 3.96us/stage) proved overlap+R7-barrier; its largest
//   remaining item is the 3-leg detect chain (~1.2us) run 6x/step when only
//   stage 7 needs a global reduction (es). Stages 1-6 consumers only need
//   "own 16 columns valid" -- tags prove that with ZERO flag/aggregator legs:
//   publish 16 (gen<<32|bits) words (no ACK), pre-build overlap (~0.3us,
//   covers store visibility), pull own 16 tagged words, retry pending-only.
//   R8 proved the tagged parity-double-buffer induction bitwise-safe; it was
//   slow only because it had no overlap and polled whole-vector per thread.
//   Stage 7 keeps R7's flag+block0+bword barrier verbatim (es, once/step,
//   on a per-step counter sgen) and pulls k7 tagged AFTER the es barrier
//   (all stores ACKed pre-flag => first sweep hits).
// R11: L2-cached pull + invalidate fence = +8ms. Bypass loads only.
// R9/R10: 512-thr workgroups cap VGPR at 128 -> Af spills; 256-thr only.
// A stays permanently in registers as fp16 (zero steady-state HBM traffic).

#define N        4096
#define NBLK     256
#define NTHR     256
#define ROWS     16          // rows of A per block (NBLK*ROWS == N)
#define MAXSTEP  512
#define PERTS    8

typedef unsigned long long ull;

static_assert(NBLK * ROWS == N, "row partition");
static_assert(NTHR * 16 == N, "column partition (4 float4 per thread)");

__device__ __forceinline__ float4 ld4(const float* p){ return *reinterpret_cast<const float4*>(p); }
__device__ __forceinline__ void   st4(float* p, float4 v){ *reinterpret_cast<float4*>(p) = v; }

__global__ void __launch_bounds__(NTHR, 1)
mbpert_rk45_kernel(const float* __restrict__ x, const int* __restrict__ tptr,
                   const float* __restrict__ r, const float* __restrict__ A,
                   const float* __restrict__ eps, const float* __restrict__ Pm,
                   float* __restrict__ out, float* __restrict__ W, int Tm)
{
  __shared__ float khist[6][N];        // 96 KB k-history (gfx950: 160KB LDS/WG)
  __shared__ float part_sm[ROWS * 4];  // per-wave matvec partials
  __shared__ float ys_rows[ROWS];      // stage vector at our 16 row indices
  __shared__ float ysb_rows[ROWS];     // base vector at our 16 row indices
  __shared__ float r_sh[ROWS];
  __shared__ float eps_sh[ROWS * PERTS];
  __shared__ float P_sh[32 * PERTS];
  __shared__ float epr_sh[ROWS];
  __shared__ float es_sh;

  const int tid = threadIdx.x;
  const int b   = blockIdx.x;
  const int rowbase = b * ROWS;
  const int lane = tid & 63;
  const int wv   = tid >> 6;

  unsigned* flags    = reinterpret_cast<unsigned*>(W);       // [256] per-block STEP flags (sgen)
  float*    err_part = W + 256;                              // [256] err partials
  ull*      bword    = reinterpret_cast<ull*>(W + 512);      // packed (sgen<<32 | err bits)
  ull*      kxt0     = reinterpret_cast<ull*>(W + 1024);     // [N] tagged k, odd gens... (parity sel below)
  ull*      kxt1     = kxt0 + N;                             // [N] tagged k, other parity

  // ---- persistent LDS constants ----
  if (tid < ROWS)             r_sh[tid]   = r[rowbase + tid];
  if (tid < ROWS * PERTS)     eps_sh[tid] = eps[rowbase * PERTS + tid];
  if (tid < (Tm + 1) * PERTS) P_sh[tid]   = Pm[tid];
  if (tid < ROWS)             ysb_rows[tid] = x[rowbase + tid];

  // ---- A fragment -> registers (fp16), once ----
  // Thread owns cols (q*256+tid)*4..+3 (q=0..3) of rows rowbase..rowbase+15.
  __half2 Af[ROWS][8];
  #pragma unroll
  for (int rr = 0; rr < ROWS; rr++){
    const float* Ar = A + (size_t)(rowbase + rr) * N;
    #pragma unroll
    for (int q = 0; q < 4; q++){
      int c = (q * NTHR + tid) * 4;
      float4 a = ld4(Ar + c);
      Af[rr][2*q]   = __floats2half2_rn(a.x, a.y);
      Af[rr][2*q+1] = __floats2half2_rn(a.z, a.w);
    }
  }

  float4 ysbf[4], ysf[4];              // base / stage vector fragments (fp32)
  #pragma unroll
  for (int q = 0; q < 4; q++) ysbf[q] = ld4(x + (q * NTHR + tid) * 4);
  __syncthreads();

  const float t_end = (float)(*tptr);
  const float Tf    = (float)Tm;
  float t = 0.0f;
  float h = t_end * 0.01f;
  unsigned gen  = 0;                   // per-exchange tag counter
  unsigned sgen = 0;                   // per-step barrier counter (stage 7)

  // matvec from registers: acc over our 16 cols, wave-reduce, park in part_sm
  auto mv = [&](){
    float acc[ROWS];
    #pragma unroll
    for (int rr = 0; rr < ROWS; rr++) acc[rr] = 0.0f;
    #pragma unroll
    for (int q = 0; q < 4; q++){
      float4 y = ysf[q];
      #pragma unroll
      for (int rr = 0; rr < ROWS; rr++){
        float2 lo = __half22float2(Af[rr][2*q]);
        float2 hi = __half22float2(Af[rr][2*q+1]);
        acc[rr] = fmaf(lo.x, y.x, fmaf(lo.y, y.y, fmaf(hi.x, y.z, fmaf(hi.y, y.w, acc[rr]))));
      }
    }
    __syncthreads();                   // part_sm free; also publishes the
                                       // preceding tagged-pull epilogue's
                                       // khist/ys_rows LDS writes
    #pragma unroll
    for (int rr = 0; rr < ROWS; rr++){
      float s = acc[rr];
      #pragma unroll
      for (int off = 32; off; off >>= 1) s += __shfl_xor(s, off, 64);
      if (lane == 0) part_sm[rr * 4 + wv] = s;
    }
    __syncthreads();
  };

  // k for row `tid` (tid<ROWS): y_s * (r + A@y_s + eps@P[d])
  auto kval = [&](float ts) -> float {
    int d = (int)((Tf * ts) / 30.0f);
    d = d < 0 ? 0 : (d > Tm ? Tm : d);
    float dot = part_sm[tid*4] + part_sm[tid*4+1] + part_sm[tid*4+2] + part_sm[tid*4+3];
    float ep = 0.f;
    #pragma unroll
    for (int p = 0; p < PERTS; p++) ep += eps_sh[tid * PERTS + p] * P_sh[d * PERTS + p];
    return ys_rows[tid] * (r_sh[tid] + dot + ep);
  };

  // classic build (stage-2 at loop head; depends on accept decision)
  auto build = [&](const int* sli, const float* cf, int nk){
    #pragma unroll
    for (int q = 0; q < 4; q++){
      int c = (q * NTHR + tid) * 4;
      float4 v = ysbf[q];
      for (int m = 0; m < nk; m++){
        float cc = h * cf[m];
        float4 kv = ld4(&khist[sli[m]][c]);
        v.x = fmaf(cc, kv.x, v.x); v.y = fmaf(cc, kv.y, v.y);
        v.z = fmaf(cc, kv.z, v.z); v.w = fmaf(cc, kv.w, v.w);
      }
      ysf[q] = v;
      int o = c - rowbase;             // c,rowbase multiples of 4/16: full containment
      if (o >= 0 && o < ROWS) st4(&ys_rows[o], v);
    }
    __syncthreads();
  };

  // tagged own-column pull into ga[4][4]; fully unrolled -> static indexing
  #define TLD(kxt, q, j) __hip_atomic_load(&(kxt)[((q) * NTHR + tid) * 4 + (j)], \
                                           __ATOMIC_RELAXED, __HIP_MEMORY_SCOPE_AGENT)
  auto pull_tagged = [&](ull* kxt, ull (&ga)[4][4]){
    unsigned pend = 0;
    #pragma unroll
    for (int q = 0; q < 4; q++)
      #pragma unroll
      for (int j = 0; j < 4; j++)
        ga[q][j] = TLD(kxt, q, j);
    #pragma unroll
    for (int q = 0; q < 4; q++)
      #pragma unroll
      for (int j = 0; j < 4; j++)
        if ((unsigned)(ga[q][j] >> 32) != gen) pend |= (1u << (q * 4 + j));
    while (pend){
      __builtin_amdgcn_s_sleep(1);
      #pragma unroll
      for (int q = 0; q < 4; q++)
        #pragma unroll
        for (int j = 0; j < 4; j++){
          if (pend & (1u << (q * 4 + j))){
            ull g = TLD(kxt, q, j);
            if ((unsigned)(g >> 32) == gen){ ga[q][j] = g; pend &= ~(1u << (q * 4 + j)); }
          }
        }
    }
  };

  // tagged exchange (stages 1..6): publish own 16 tagged k's (no ACK, no
  // flag), pre-build NEXT stage's ys from OLD slots while stores propagate,
  // then pull own columns by tag (retry pending-only), consume the new k
  // from registers (always the LAST coefficient -> bitwise-same fma order),
  // park it in khist[slot_in] off the critical path (mv barrier publishes).
  auto exchange_build_t = [&](int slot_in, float kv,
                              const int* sli_old, const float* cf_old, int nk_old,
                              float cf_new){
    ++gen;
    ull* kxt = (gen & 1u) ? kxt1 : kxt0;         // double buffer by parity
    if (wv == 0 && lane < ROWS)
      __hip_atomic_store(&kxt[rowbase + lane],
                         (((ull)gen) << 32) | (ull)__float_as_uint(kv),
                         __ATOMIC_RELAXED, __HIP_MEMORY_SCOPE_AGENT);
    #pragma unroll
    for (int q = 0; q < 4; q++){                 // partial: old slots (stable LDS)
      int c = (q * NTHR + tid) * 4;
      float4 v = ysbf[q];
      for (int m = 0; m < nk_old; m++){
        float cc = h * cf_old[m];
        float4 kvv = ld4(&khist[sli_old[m]][c]);
        v.x = fmaf(cc, kvv.x, v.x); v.y = fmaf(cc, kvv.y, v.y);
        v.z = fmaf(cc, kvv.z, v.z); v.w = fmaf(cc, kvv.w, v.w);
      }
      ysf[q] = v;
    }
    ull ga[4][4];
    pull_tagged(kxt, ga);
    const float cc = h * cf_new;
    #pragma unroll
    for (int q = 0; q < 4; q++){                 // consume from registers
      int c = (q * NTHR + tid) * 4;
      float k0 = __uint_as_float((unsigned)ga[q][0]);
      float k1 = __uint_as_float((unsigned)ga[q][1]);
      float k2 = __uint_as_float((unsigned)ga[q][2]);
      float k3 = __uint_as_float((unsigned)ga[q][3]);
      float4 v = ysf[q];
      v.x = fmaf(cc, k0, v.x); v.y = fmaf(cc, k1, v.y);
      v.z = fmaf(cc, k2, v.z); v.w = fmaf(cc, k3, v.w);
      ysf[q] = v;
      st4(&khist[slot_in][c], make_float4(k0, k1, k2, k3));
      int o = c - rowbase;
      if (o >= 0 && o < ROWS) st4(&ys_rows[o], v);
    }
    // no trailing __syncthreads: mv()'s first barrier publishes khist/ys_rows
    // (slot_in is dead to every partial-build list in this step).
  };

  // stage-7 exchange: tagged k7 publish + R7 es-barrier (sgen) + tagged pull.
  auto exchange7 = [&](int slot, float k7v, float errv){
    ++gen; ++sgen;
    ull* kxt = (gen & 1u) ? kxt1 : kxt0;
    if (wv == 0){
      if (lane < ROWS)
        __hip_atomic_store(&kxt[rowbase + lane],
                           (((ull)gen) << 32) | (ull)__float_as_uint(k7v),
                           __ATOMIC_RELAXED, __HIP_MEMORY_SCOPE_AGENT);
      if (lane == 0)
        __hip_atomic_store(&err_part[b], errv, __ATOMIC_RELAXED, __HIP_MEMORY_SCOPE_AGENT);
    }
    __syncthreads();                             // all stage work done
    if (tid == 0){
      __builtin_amdgcn_sched_barrier(0);
      __builtin_amdgcn_s_waitcnt(0);             // kxt/err stores at coherence point
      __builtin_amdgcn_sched_barrier(0);
      __hip_atomic_store(&flags[b], sgen, __ATOMIC_RELAXED, __HIP_MEMORY_SCOPE_AGENT);
    }
    if (b == 0){
      // ---- aggregator: scan all 256 step-flags, broadcast packed (sgen,es) ----
      if (wv == 0){
        for (;;){
          bool ok = true;
          #pragma unroll
          for (int j = 0; j < 4; j++){
            unsigned f = __hip_atomic_load(&flags[j * 64 + lane],
                                           __ATOMIC_RELAXED, __HIP_MEMORY_SCOPE_AGENT);
            ok = ok && (f >= sgen);
          }
          if (__all(ok)) break;
          __builtin_amdgcn_s_sleep(2);
        }
        float es = 0.f;
        #pragma unroll
        for (int j = 0; j < 4; j++)              // R7 order -> bitwise identical
          es += __hip_atomic_load(&err_part[lane + j * 64],
                                  __ATOMIC_RELAXED, __HIP_MEMORY_SCOPE_AGENT);
        #pragma unroll
        for (int off = 32; off; off >>= 1) es += __shfl_xor(es, off, 64);
        if (lane == 0){
          es_sh = es;
          ull pk = ((ull)sgen << 32) | (ull)__float_as_uint(es);
          __builtin_amdgcn_sched_barrier(0);
          __builtin_amdgcn_s_waitcnt(0);
          __builtin_amdgcn_sched_barrier(0);
          __hip_atomic_store(bword, pk, __ATOMIC_RELAXED, __HIP_MEMORY_SCOPE_AGENT);
        }
      }
      __syncthreads();
    } else {
      // ---- follower: poll the single broadcast word ----
      if (tid == 0){
        for (;;){
          ull w = __hip_atomic_load(bword, __ATOMIC_RELAXED, __HIP_MEMORY_SCOPE_AGENT);
          if ((unsigned)(w >> 32) >= sgen){
            es_sh = __uint_as_float((unsigned)(w & 0xffffffffu));
            break;
          }
          __builtin_amdgcn_s_sleep(2);
        }
      }
      __syncthreads();
    }
    // ---- tagged pull of k7 (all stores ACKed pre-flag => first sweep hits) ----
    ull ga[4][4];
    pull_tagged(kxt, ga);
    #pragma unroll
    for (int q = 0; q < 4; q++){
      int c = (q * NTHR + tid) * 4;
      st4(&khist[slot][c], make_float4(__uint_as_float((unsigned)ga[q][0]),
                                       __uint_as_float((unsigned)ga[q][1]),
                                       __uint_as_float((unsigned)ga[q][2]),
                                       __uint_as_float((unsigned)ga[q][3])));
    }
    __syncthreads();                             // khist[slot]/es_sh ready
  };

  int sl[6] = {0, 1, 2, 3, 4, 5};      // logical k1..k6 -> physical LDS slots
  bool exhausted = true;

  for (int n = 0; n < MAXSTEP; ++n){
    if (n > 0){
      float es = es_sh;                          // set by last stage-7 exchange
      float enorm = sqrtf(es * (1.0f / (float)N));
      bool accept = (enorm <= 1.0f);
      if (accept){
        t += h;
        int tmp = sl[0]; sl[0] = sl[1]; sl[1] = tmp;  // FSAL: k1 <- k7 (in k2's slot)
        #pragma unroll
        for (int q = 0; q < 4; q++) ysbf[q] = ysf[q];
        if (tid < ROWS) ysb_rows[tid] = ys_rows[tid];
      }
      float fac = 0.9f * powf(enorm + 1e-10f, -0.2f);
      fac = fminf(fmaxf(fac, 0.2f), 10.0f);
      h *= fac;
      __syncthreads();
      if (t >= t_end) { exhausted = false; break; }
      h = fminf(h, t_end - t);
      if (!(h > 0.0f)) { exhausted = false; break; }
      // ---- stage-2 build (classic; depends on accept decision) ----
      { const float cf[1] = {0.2f}; const int s_[1] = {sl[0]};
        build(s_, cf, 1); }
    } else {
      if (t >= t_end) { exhausted = false; break; }
      h = fminf(h, t_end - t);
      if (!(h > 0.0f)) { exhausted = false; break; }
      // ---- stage 1 (once ever; FSAL covers later steps) ----
      #pragma unroll
      for (int q = 0; q < 4; q++){
        ysf[q] = ysbf[q];
        int c = (q * NTHR + tid) * 4, o = c - rowbase;
        if (o >= 0 && o < ROWS) st4(&ys_rows[o], ysf[q]);
      }
      __syncthreads();
      mv();
      float kv = (tid < ROWS) ? kval(t) : 0.f;
      exchange_build_t(sl[0], kv, nullptr, nullptr, 0, 0.2f);  // builds stage-2 ys
    }

    // ---- stage 2: publish k2, pre-build stage-3 ys ----
    mv();
    { float kv = (tid < ROWS) ? kval(t + 0.2f * h) : 0.f;
      const int s_[1] = {sl[0]}; const float cf[1] = {3.f/40.f};
      exchange_build_t(sl[1], kv, s_, cf, 1, 9.f/40.f); }

    // ---- stage 3: publish k3, pre-build stage-4 ys ----
    mv();
    { float kv = (tid < ROWS) ? kval(t + 0.3f * h) : 0.f;
      const int s_[2] = {sl[0], sl[1]}; const float cf[2] = {44.f/45.f, -56.f/15.f};
      exchange_build_t(sl[2], kv, s_, cf, 2, 32.f/9.f); }

    // ---- stage 4: publish k4, pre-build stage-5 ys ----
    mv();
    { float kv = (tid < ROWS) ? kval(t + 0.8f * h) : 0.f;
      const int s_[3] = {sl[0], sl[1], sl[2]};
      const float cf[3] = {19372.f/6561.f, -25360.f/2187.f, 64448.f/6561.f};
      exchange_build_t(sl[3], kv, s_, cf, 3, -212.f/729.f); }

    // ---- stage 5: publish k5, pre-build stage-6 ys ----
    mv();
    { float kv = (tid < ROWS) ? kval(t + (8.f/9.f) * h) : 0.f;
      const int s_[4] = {sl[0], sl[1], sl[2], sl[3]};
      const float cf[4] = {9017.f/3168.f, -355.f/33.f, 46732.f/5247.f, 49.f/176.f};
      exchange_build_t(sl[4], kv, s_, cf, 4, -5103.f/18656.f); }

    // ---- stage 6: publish k6, pre-build stage-7 ys (= y5 candidate) ----
    mv();
    { float kv = (tid < ROWS) ? kval(t + h) : 0.f;
      const int s_[4] = {sl[0], sl[2], sl[3], sl[4]};
      const float cf[4] = {35.f/384.f, 500.f/1113.f, 125.f/192.f, -2187.f/6784.f};
      exchange_build_t(sl[5], kv, s_, cf, 4, 11.f/84.f); }

    // ---- stage 7: err partial; hybrid exchange (k7 -> sl[1], k2 dead) ----
    mv();
    { float k7v = 0.f, errv = 0.f;
      if (tid < ROWS){
        k7v = kval(t + h);
        int gi = rowbase + tid;
        float e = (71.f/57600.f)  * khist[sl[0]][gi] - (71.f/16695.f)    * khist[sl[2]][gi]
                + (71.f/1920.f)   * khist[sl[3]][gi] - (17253.f/339200.f)* khist[sl[4]][gi]
                + (22.f/525.f)    * khist[sl[5]][gi] - (1.f/40.f)        * k7v;
        e *= h;
        float sc = 1e-6f + 1e-3f * fmaxf(fabsf(ysb_rows[tid]), fabsf(ys_rows[tid]));
        float q = e / sc;
        epr_sh[tid] = q * q;
      }
      __syncthreads();
      if (tid == 0){
        float s = 0.f;
        #pragma unroll
        for (int i = 0; i < ROWS; i++) s += epr_sh[i];
        errv = s;
      }
      exchange7(sl[1], k7v, errv); }             // es barrier + tagged k7 fetch
  }

  if (exhausted){
    // apply the final (iteration 511) accept decision, as the reference does
    float es = es_sh;
    bool accept = sqrtf(es * (1.0f / (float)N)) <= 1.0f;
    if (tid < ROWS) out[rowbase + tid] = accept ? ys_rows[tid] : ysb_rows[tid];
  } else {
    if (tid < ROWS) out[rowbase + tid] = ysb_rows[tid];
  }
}

extern "C" void kernel_launch(void* const* d_in, const int* in_sizes, int n_in,
                              void* d_out, int out_size, void* d_ws, size_t ws_size,
                              hipStream_t stream)
{
  const float* x   = (const float*)d_in[0];
  const int*   tp  = (const int*)  d_in[1];
  const float* r   = (const float*)d_in[2];
  const float* A   = (const float*)d_in[3];
  const float* eps = (const float*)d_in[4];
  const float* Pm  = (const float*)d_in[5];
  float* out = (float*)d_out;
  float* W   = (float*)d_ws;
  int Tm = in_sizes[5] / PERTS - 1;   // P rows - 1  (== 30)

  // zero flags/err/bword (4KB) AND both tagged k buffers (2 x 32KB): poison
  // bytes could otherwise alias a valid gen tag.
  hipMemsetAsync(d_ws, 0, 4096 + 2 * (size_t)N * sizeof(ull), stream);
  mbpert_rk45_kernel<<<dim3(NBLK), dim3(NTHR), 0, stream>>>(
      x, tp, r, A, eps, Pm, out, W, Tm);
}

// Round 9
// 12351.382 us; speedup vs baseline: 1.1824x; 1.1824x over previous
//
#include <hip/hip_runtime.h>
#include <hip/hip_fp16.h>
#include <math.h>

// Persistent RK45 (Dormand-Prince, FSAL) integrator for
//   dy/dt = y * (r + A@y + eps@P[d(t)]),  n=4096, up to 512 adaptive steps.
// R16 = R14 (12.37ms best) with three chain-latency cuts, same shape:
//  (a) stages 1-6 publish WITHOUT the intra-block barrier: only wave0
//      publishes and s_waitcnt is wave-scoped, so wave0 does store->ACK->flag
//      autonomously while waves 1-3 start the pre-build immediately. Flag
//      leaves ~0.3-0.4us earlier => direct cut of the global serial chain.
//      (WAR induction unchanged: gen-publish still follows own gen-1 pull;
//      flag still certifies publish completion.)
//  (b) block0's bword store drops its waitcnt: the (gen|es) word is a single
//      self-contained 8B atomic store -- nothing to order before it.
//  (c) poll sleep 2->1 (halves catch quantization).
// Stage 7 keeps R14/R7 structure verbatim (needs the epr_sh barrier anyway).
// Ledger: R7 4.34us/stage | R8 tagged 4.37 (congestion) | R12 flat-scan 4.55
//   | R13 counter 4.87 | R14 overlap+R7barrier 3.96 | R15 tagged+overlap 4.75
//   (1M-load sweeps + VGPR 248 spill). LAW (R8/R12/R15): only <=1 wave/block
//   may poll, against <=a-few words. R11: no cached pulls (invalidate serial).
// R9/R10: 512-thr workgroups cap VGPR at 128 -> Af spills; 256-thr only.
// A stays permanently in registers as fp16 (zero steady-state HBM traffic).

#define N        4096
#define NBLK     256
#define NTHR     256
#define ROWS     16          // rows of A per block (NBLK*ROWS == N)
#define MAXSTEP  512
#define PERTS    8

typedef unsigned long long ull;

static_assert(NBLK * ROWS == N, "row partition");
static_assert(NTHR * 16 == N, "column partition (4 float4 per thread)");

__device__ __forceinline__ float4 ld4(const float* p){ return *reinterpret_cast<const float4*>(p); }
__device__ __forceinline__ void   st4(float* p, float4 v){ *reinterpret_cast<float4*>(p) = v; }

__global__ void __launch_bounds__(NTHR, 1)
mbpert_rk45_kernel(const float* __restrict__ x, const int* __restrict__ tptr,
                   const float* __restrict__ r, const float* __restrict__ A,
                   const float* __restrict__ eps, const float* __restrict__ Pm,
                   float* __restrict__ out, float* __restrict__ W, int Tm)
{
  __shared__ float khist[6][N];        // 96 KB k-history (gfx950: 160KB LDS/WG)
  __shared__ float part_sm[ROWS * 4];  // per-wave matvec partials
  __shared__ float ys_rows[ROWS];      // stage vector at our 16 row indices
  __shared__ float ysb_rows[ROWS];     // base vector at our 16 row indices
  __shared__ float r_sh[ROWS];
  __shared__ float eps_sh[ROWS * PERTS];
  __shared__ float P_sh[32 * PERTS];
  __shared__ float epr_sh[ROWS];
  __shared__ float es_sh;

  const int tid = threadIdx.x;
  const int b   = blockIdx.x;
  const int rowbase = b * ROWS;
  const int lane = tid & 63;
  const int wv   = tid >> 6;

  unsigned* flags    = reinterpret_cast<unsigned*>(W);       // [256] per-block stage flags
  float*    err_part = W + 256;                              // [256] err partials
  ull*      bword    = reinterpret_cast<ull*>(W + 512);      // packed (gen<<32 | err bits)
  ull*      kx0u     = reinterpret_cast<ull*>(W + 1024);     // [N/2] exchange buf A
  ull*      kx1u     = reinterpret_cast<ull*>(W + 1024 + N); // [N/2] exchange buf B

  // ---- persistent LDS constants ----
  if (tid < ROWS)             r_sh[tid]   = r[rowbase + tid];
  if (tid < ROWS * PERTS)     eps_sh[tid] = eps[rowbase * PERTS + tid];
  if (tid < (Tm + 1) * PERTS) P_sh[tid]   = Pm[tid];
  if (tid < ROWS)             ysb_rows[tid] = x[rowbase + tid];

  // ---- A fragment -> registers (fp16), once ----
  // Thread owns cols (q*256+tid)*4..+3 (q=0..3) of rows rowbase..rowbase+15.
  __half2 Af[ROWS][8];
  #pragma unroll
  for (int rr = 0; rr < ROWS; rr++){
    const float* Ar = A + (size_t)(rowbase + rr) * N;
    #pragma unroll
    for (int q = 0; q < 4; q++){
      int c = (q * NTHR + tid) * 4;
      float4 a = ld4(Ar + c);
      Af[rr][2*q]   = __floats2half2_rn(a.x, a.y);
      Af[rr][2*q+1] = __floats2half2_rn(a.z, a.w);
    }
  }

  float4 ysbf[4], ysf[4];              // base / stage vector fragments (fp32)
  #pragma unroll
  for (int q = 0; q < 4; q++) ysbf[q] = ld4(x + (q * NTHR + tid) * 4);
  __syncthreads();

  const float t_end = (float)(*tptr);
  const float Tf    = (float)Tm;
  float t = 0.0f;
  float h = t_end * 0.01f;
  unsigned gen = 0;

  // matvec from registers: acc over our 16 cols, wave-reduce, park in part_sm
  auto mv = [&](){
    float acc[ROWS];
    #pragma unroll
    for (int rr = 0; rr < ROWS; rr++) acc[rr] = 0.0f;
    #pragma unroll
    for (int q = 0; q < 4; q++){
      float4 y = ysf[q];
      #pragma unroll
      for (int rr = 0; rr < ROWS; rr++){
        float2 lo = __half22float2(Af[rr][2*q]);
        float2 hi = __half22float2(Af[rr][2*q+1]);
        acc[rr] = fmaf(lo.x, y.x, fmaf(lo.y, y.y, fmaf(hi.x, y.z, fmaf(hi.y, y.w, acc[rr]))));
      }
    }
    __syncthreads();                   // part_sm free; also publishes the
                                       // preceding exchange_build epilogue's
                                       // khist/ys_rows LDS writes
    #pragma unroll
    for (int rr = 0; rr < ROWS; rr++){
      float s = acc[rr];
      #pragma unroll
      for (int off = 32; off; off >>= 1) s += __shfl_xor(s, off, 64);
      if (lane == 0) part_sm[rr * 4 + wv] = s;
    }
    __syncthreads();
  };

  // k for row `tid` (tid<ROWS): y_s * (r + A@y_s + eps@P[d])
  auto kval = [&](float ts) -> float {
    int d = (int)((Tf * ts) / 30.0f);
    d = d < 0 ? 0 : (d > Tm ? Tm : d);
    float dot = part_sm[tid*4] + part_sm[tid*4+1] + part_sm[tid*4+2] + part_sm[tid*4+3];
    float ep = 0.f;
    #pragma unroll
    for (int p = 0; p < PERTS; p++) ep += eps_sh[tid * PERTS + p] * P_sh[d * PERTS + p];
    return ys_rows[tid] * (r_sh[tid] + dot + ep);
  };

  // classic build (stage-2 at loop head; depends on accept decision)
  auto build = [&](const int* sli, const float* cf, int nk){
    #pragma unroll
    for (int q = 0; q < 4; q++){
      int c = (q * NTHR + tid) * 4;
      float4 v = ysbf[q];
      for (int m = 0; m < nk; m++){
        float cc = h * cf[m];
        float4 kv = ld4(&khist[sli[m]][c]);
        v.x = fmaf(cc, kv.x, v.x); v.y = fmaf(cc, kv.y, v.y);
        v.z = fmaf(cc, kv.z, v.z); v.w = fmaf(cc, kv.w, v.w);
      }
      ysf[q] = v;
      int o = c - rowbase;             // c,rowbase multiples of 4/16: full containment
      if (o >= 0 && o < ROWS) st4(&ys_rows[o], v);
    }
    __syncthreads();
  };

  // FAST publish (stages 1-6): wave0 autonomously stores k, ACKs (wave-scoped
  // waitcnt), and raises the flag -- NO intra-block barrier. Waves 1-3 are
  // already running the pre-build when the flag leaves the block.
  auto publish_fast = [&](float kv) -> ull* {
    ++gen;
    ull* kx = (gen & 1u) ? kx1u : kx0u;          // double buffer by parity
    if (wv == 0){
      float kvn = __shfl_down(kv, 1, 64);
      if ((lane & 1) == 0 && lane < ROWS){
        union { float2 f; ull u; } cv;
        cv.f = make_float2(kv, kvn);
        __hip_atomic_store(&kx[(rowbase >> 1) + (lane >> 1)], cv.u,
                           __ATOMIC_RELAXED, __HIP_MEMORY_SCOPE_AGENT);
      }
      __builtin_amdgcn_sched_barrier(0);
      __builtin_amdgcn_s_waitcnt(0);             // wave0's k stores at coherence point
      __builtin_amdgcn_sched_barrier(0);
      if (lane == 0)
        __hip_atomic_store(&flags[b], gen, __ATOMIC_RELAXED, __HIP_MEMORY_SCOPE_AGENT);
    }
    return kx;
  };

  // R7 publish (stage 7): barrier'd (epr_sh aggregation precedes errv anyway)
  auto publish_flag = [&](float kv, bool werr, float errv) -> ull* {
    ++gen;
    ull* kx = (gen & 1u) ? kx1u : kx0u;          // double buffer by parity
    if (wv == 0){
      float kvn = __shfl_down(kv, 1, 64);
      if ((lane & 1) == 0 && lane < ROWS){
        union { float2 f; ull u; } cv;
        cv.f = make_float2(kv, kvn);
        __hip_atomic_store(&kx[(rowbase >> 1) + (lane >> 1)], cv.u,
                           __ATOMIC_RELAXED, __HIP_MEMORY_SCOPE_AGENT);
      }
      if (werr && lane == 0)
        __hip_atomic_store(&err_part[b], errv, __ATOMIC_RELAXED, __HIP_MEMORY_SCOPE_AGENT);
    }
    __syncthreads();                             // all stage work done
    if (tid == 0){
      __builtin_amdgcn_sched_barrier(0);
      __builtin_amdgcn_s_waitcnt(0);             // kx/err stores at coherence point
      __builtin_amdgcn_sched_barrier(0);
      __hip_atomic_store(&flags[b], gen, __ATOMIC_RELAXED, __HIP_MEMORY_SCOPE_AGENT);
    }
    return kx;
  };

  // R7 detect: block0 scans all flags, broadcasts one packed (gen,err) word.
  // bword store needs NO waitcnt: it is a single self-contained 8B atomic.
  auto detect = [&](bool werr){
    if (b == 0){
      if (wv == 0){
        for (;;){
          bool ok = true;
          #pragma unroll
          for (int j = 0; j < 4; j++){
            unsigned f = __hip_atomic_load(&flags[j * 64 + lane],
                                           __ATOMIC_RELAXED, __HIP_MEMORY_SCOPE_AGENT);
            ok = ok && (f >= gen);
          }
          if (__all(ok)) break;
          __builtin_amdgcn_s_sleep(1);
        }
        float es = 0.f;
        if (werr){                               // R7 order -> bitwise identical
          #pragma unroll
          for (int j = 0; j < 4; j++)
            es += __hip_atomic_load(&err_part[lane + j * 64],
                                    __ATOMIC_RELAXED, __HIP_MEMORY_SCOPE_AGENT);
          #pragma unroll
          for (int off = 32; off; off >>= 1) es += __shfl_xor(es, off, 64);
        }
        if (lane == 0){
          if (werr) es_sh = es;
          ull pk = ((ull)gen << 32) | (ull)__float_as_uint(es);
          __hip_atomic_store(bword, pk, __ATOMIC_RELAXED, __HIP_MEMORY_SCOPE_AGENT);
        }
      }
      __syncthreads();
    } else {
      if (tid == 0){
        for (;;){
          ull w = __hip_atomic_load(bword, __ATOMIC_RELAXED, __HIP_MEMORY_SCOPE_AGENT);
          if ((unsigned)(w >> 32) >= gen){
            if (werr) es_sh = __uint_as_float((unsigned)(w & 0xffffffffu));
            break;
          }
          __builtin_amdgcn_s_sleep(1);
        }
      }
      __syncthreads();
    }
  };

  // classic exchange (stage 7): publish, detect(+err), pull full k into LDS
  auto exchange = [&](int slot, float kv, bool werr, float errv){
    ull* kx = publish_flag(kv, werr, errv);
    detect(werr);
    float2* kh2 = reinterpret_cast<float2*>(&khist[slot][0]);
    #pragma unroll
    for (int i = 0; i < 8; i++){                 // coalesced dwordx2 atomic loads
      union { float2 f; ull u; } cv;
      cv.u = __hip_atomic_load(&kx[i * NTHR + tid], __ATOMIC_RELAXED, __HIP_MEMORY_SCOPE_AGENT);
      kh2[i * NTHR + tid] = cv.f;
    }
    __syncthreads();                             // khist[slot]/es_sh ready
  };

  // overlapped exchange (stages 1..6): fast publish (wave0 autonomous), all
  // waves pre-build NEXT stage's ys from OLD slots during flag/detect, then
  // consume the new k from registers (always the LAST coefficient ->
  // bitwise-same fma order), park it in khist[slot_in] off the critical path.
  auto exchange_build = [&](int slot_in, float kv,
                            const int* sli_old, const float* cf_old, int nk_old,
                            float cf_new){
    ull* kx = publish_fast(kv);
    #pragma unroll
    for (int q = 0; q < 4; q++){                 // partial: old slots (stable LDS)
      int c = (q * NTHR + tid) * 4;
      float4 v = ysbf[q];
      for (int m = 0; m < nk_old; m++){
        float cc = h * cf_old[m];
        float4 kvv = ld4(&khist[sli_old[m]][c]);
        v.x = fmaf(cc, kvv.x, v.x); v.y = fmaf(cc, kvv.y, v.y);
        v.z = fmaf(cc, kvv.z, v.z); v.w = fmaf(cc, kvv.w, v.w);
      }
      ysf[q] = v;
    }
    detect(false);
    const float cc = h * cf_new;
    #pragma unroll
    for (int q = 0; q < 4; q++){                 // pull OWN columns, fma from regs
      int c = (q * NTHR + tid) * 4;
      union { float2 f; ull u; } c0, c1;
      c0.u = __hip_atomic_load(&kx[(c >> 1)],     __ATOMIC_RELAXED, __HIP_MEMORY_SCOPE_AGENT);
      c1.u = __hip_atomic_load(&kx[(c >> 1) + 1], __ATOMIC_RELAXED, __HIP_MEMORY_SCOPE_AGENT);
      float4 v = ysf[q];
      v.x = fmaf(cc, c0.f.x, v.x); v.y = fmaf(cc, c0.f.y, v.y);
      v.z = fmaf(cc, c1.f.x, v.z); v.w = fmaf(cc, c1.f.y, v.w);
      ysf[q] = v;
      st4(&khist[slot_in][c], make_float4(c0.f.x, c0.f.y, c1.f.x, c1.f.y));
      int o = c - rowbase;
      if (o >= 0 && o < ROWS) st4(&ys_rows[o], v);
    }
    // no trailing __syncthreads: mv()'s first barrier publishes khist/ys_rows
    // (slot_in is dead to every partial-build list in this step).
  };

  int sl[6] = {0, 1, 2, 3, 4, 5};      // logical k1..k6 -> physical LDS slots
  bool exhausted = true;

  for (int n = 0; n < MAXSTEP; ++n){
    if (n > 0){
      float es = es_sh;                          // set by last stage-7 exchange
      float enorm = sqrtf(es * (1.0f / (float)N));
      bool accept = (enorm <= 1.0f);
      if (accept){
        t += h;
        int tmp = sl[0]; sl[0] = sl[1]; sl[1] = tmp;  // FSAL: k1 <- k7 (in k2's slot)
        #pragma unroll
        for (int q = 0; q < 4; q++) ysbf[q] = ysf[q];
        if (tid < ROWS) ysb_rows[tid] = ys_rows[tid];
      }
      float fac = 0.9f * powf(enorm + 1e-10f, -0.2f);
      fac = fminf(fmaxf(fac, 0.2f), 10.0f);
      h *= fac;
      __syncthreads();
      if (t >= t_end) { exhausted = false; break; }
      h = fminf(h, t_end - t);
      if (!(h > 0.0f)) { exhausted = false; break; }
      // ---- stage-2 build (classic; depends on accept decision) ----
      { const float cf[1] = {0.2f}; const int s_[1] = {sl[0]};
        build(s_, cf, 1); }
    } else {
      if (t >= t_end) { exhausted = false; break; }
      h = fminf(h, t_end - t);
      if (!(h > 0.0f)) { exhausted = false; break; }
      // ---- stage 1 (once ever; FSAL covers later steps) ----
      #pragma unroll
      for (int q = 0; q < 4; q++){
        ysf[q] = ysbf[q];
        int c = (q * NTHR + tid) * 4, o = c - rowbase;
        if (o >= 0 && o < ROWS) st4(&ys_rows[o], ysf[q]);
      }
      __syncthreads();
      mv();
      float kv = (tid < ROWS) ? kval(t) : 0.f;
      exchange_build(sl[0], kv, nullptr, nullptr, 0, 0.2f);   // builds stage-2 ys
    }

    // ---- stage 2: publish k2, pre-build stage-3 ys ----
    mv();
    { float kv = (tid < ROWS) ? kval(t + 0.2f * h) : 0.f;
      const int s_[1] = {sl[0]}; const float cf[1] = {3.f/40.f};
      exchange_build(sl[1], kv, s_, cf, 1, 9.f/40.f); }

    // ---- stage 3: publish k3, pre-build stage-4 ys ----
    mv();
    { float kv = (tid < ROWS) ? kval(t + 0.3f * h) : 0.f;
      const int s_[2] = {sl[0], sl[1]}; const float cf[2] = {44.f/45.f, -56.f/15.f};
      exchange_build(sl[2], kv, s_, cf, 2, 32.f/9.f); }

    // ---- stage 4: publish k4, pre-build stage-5 ys ----
    mv();
    { float kv = (tid < ROWS) ? kval(t + 0.8f * h) : 0.f;
      const int s_[3] = {sl[0], sl[1], sl[2]};
      const float cf[3] = {19372.f/6561.f, -25360.f/2187.f, 64448.f/6561.f};
      exchange_build(sl[3], kv, s_, cf, 3, -212.f/729.f); }

    // ---- stage 5: publish k5, pre-build stage-6 ys ----
    mv();
    { float kv = (tid < ROWS) ? kval(t + (8.f/9.f) * h) : 0.f;
      const int s_[4] = {sl[0], sl[1], sl[2], sl[3]};
      const float cf[4] = {9017.f/3168.f, -355.f/33.f, 46732.f/5247.f, 49.f/176.f};
      exchange_build(sl[4], kv, s_, cf, 4, -5103.f/18656.f); }

    // ---- stage 6: publish k6, pre-build stage-7 ys (= y5 candidate) ----
    mv();
    { float kv = (tid < ROWS) ? kval(t + h) : 0.f;
      const int s_[4] = {sl[0], sl[2], sl[3], sl[4]};
      const float cf[4] = {35.f/384.f, 500.f/1113.f, 125.f/192.f, -2187.f/6784.f};
      exchange_build(sl[5], kv, s_, cf, 4, 11.f/84.f); }

    // ---- stage 7: err partial; classic exchange (k7 -> sl[1], k2 dead) ----
    mv();
    { float k7v = 0.f, errv = 0.f;
      if (tid < ROWS){
        k7v = kval(t + h);
        int gi = rowbase + tid;
        float e = (71.f/57600.f)  * khist[sl[0]][gi] - (71.f/16695.f)    * khist[sl[2]][gi]
                + (71.f/1920.f)   * khist[sl[3]][gi] - (17253.f/339200.f)* khist[sl[4]][gi]
                + (22.f/525.f)    * khist[sl[5]][gi] - (1.f/40.f)        * k7v;
        e *= h;
        float sc = 1e-6f + 1e-3f * fmaxf(fabsf(ysb_rows[tid]), fabsf(ys_rows[tid]));
        float q = e / sc;
        epr_sh[tid] = q * q;
      }
      __syncthreads();
      if (tid == 0){
        float s = 0.f;
        #pragma unroll
        for (int i = 0; i < ROWS; i++) s += epr_sh[i];
        errv = s;
      }
      exchange(sl[1], k7v, true, errv); }        // barrier + err broadcast + k7 fetch
  }

  if (exhausted){
    // apply the final (iteration 511) accept decision, as the reference does
    float es = es_sh;
    bool accept = sqrtf(es * (1.0f / (float)N)) <= 1.0f;
    if (tid < ROWS) out[rowbase + tid] = accept ? ys_rows[tid] : ysb_rows[tid];
  } else {
    if (tid < ROWS) out[rowbase + tid] = ysb_rows[tid];
  }
}

extern "C" void kernel_launch(void* const* d_in, const int* in_sizes, int n_in,
                              void* d_out, int out_size, void* d_ws, size_t ws_size,
                              hipStream_t stream)
{
  const float* x   = (const float*)d_in[0];
  const int*   tp  = (const int*)  d_in[1];
  const float* r   = (const float*)d_in[2];
  const float* A   = (const float*)d_in[3];
  const float* eps = (const float*)d_in[4];
  const float* Pm  = (const float*)d_in[5];
  float* out = (float*)d_out;
  float* W   = (float*)d_ws;
  int Tm = in_sizes[5] / PERTS - 1;   // P rows - 1  (== 30)

  // zero flags / err partials / broadcast word (ws re-poisoned per call)
  hipMemsetAsync(d_ws, 0, 4096, stream);
  mbpert_rk45_kernel<<<dim3(NBLK), dim3(NTHR), 0, stream>>>(
      x, tp, r, A, eps, Pm, out, W, Tm);
}

// Round 10
// 12257.654 us; speedup vs baseline: 1.1915x; 1.0076x over previous
//
#include <hip/hip_runtime.h>
#include <hip/hip_fp16.h>
#include <math.h>

// Persistent RK45 (Dormand-Prince, FSAL) integrator for
//   dy/dt = y * (r + A@y + eps@P[d(t)]),  n=4096, up to 512 adaptive steps.
// R17 = R16 (12.02ms steady, best) + two shape-preserving cuts:
//  (a) 8-way bword replication: block0's wave0 lanes 0-7 store the packed
//      (gen|es) word to 8 separate lines; follower b polls bword8[b&7]
//      (<=32 readers/line vs 255). Targets hot-line service serialization
//      at the coherence point -- the only leg left that can be >0.3us.
//  (b) part_sm double-buffer -> drop mv()'s first __syncthreads (it only
//      protected part_sm WAR between consecutive stages; banks alternate).
// R16 lesson: intra-block publish barrier was NOT on the critical path
//   (-0.05us vs predicted -0.3); chain is CP-side (visibility+catch+bulk).
// Ledger (us/stage): R7 4.34 | R8 tagged 4.37 | R12 flat-scan 4.55 | R13
//   counter 4.87 | R14 overlap+relay 3.96 | R15 tagged+overlap 4.75 | R16
//   3.91. LAWS: <=1 wave/block polls <=few words (R8/R12/R15); no cached
//   pulls (R11: invalidates serialize, +2.6us/stage); 256-thr blocks only
//   (R9/R10: 512-thr caps VGPR at 128 -> Af spills).
// A stays permanently in registers as fp16 (zero steady-state HBM traffic).

#define N        4096
#define NBLK     256
#define NTHR     256
#define ROWS     16          // rows of A per block (NBLK*ROWS == N)
#define MAXSTEP  512
#define PERTS    8

typedef unsigned long long ull;

static_assert(NBLK * ROWS == N, "row partition");
static_assert(NTHR * 16 == N, "column partition (4 float4 per thread)");

__device__ __forceinline__ float4 ld4(const float* p){ return *reinterpret_cast<const float4*>(p); }
__device__ __forceinline__ void   st4(float* p, float4 v){ *reinterpret_cast<float4*>(p) = v; }

__global__ void __launch_bounds__(NTHR, 1)
mbpert_rk45_kernel(const float* __restrict__ x, const int* __restrict__ tptr,
                   const float* __restrict__ r, const float* __restrict__ A,
                   const float* __restrict__ eps, const float* __restrict__ Pm,
                   float* __restrict__ out, float* __restrict__ W, int Tm)
{
  __shared__ float khist[6][N];        // 96 KB k-history (gfx950: 160KB LDS/WG)
  __shared__ float part_sm[2][ROWS * 4];  // DOUBLE-BUFFERED per-wave matvec partials
  __shared__ float ys_rows[ROWS];      // stage vector at our 16 row indices
  __shared__ float ysb_rows[ROWS];     // base vector at our 16 row indices
  __shared__ float r_sh[ROWS];
  __shared__ float eps_sh[ROWS * PERTS];
  __shared__ float P_sh[32 * PERTS];
  __shared__ float epr_sh[ROWS];
  __shared__ float es_sh;

  const int tid = threadIdx.x;
  const int b   = blockIdx.x;
  const int rowbase = b * ROWS;
  const int lane = tid & 63;
  const int wv   = tid >> 6;

  unsigned* flags    = reinterpret_cast<unsigned*>(W);       // [256] per-block stage flags
  float*    err_part = W + 256;                              // [256] err partials
  ull*      bword8   = reinterpret_cast<ull*>(W + 512);      // [8] replicated (gen<<32|err)
  ull*      kx0u     = reinterpret_cast<ull*>(W + 1024);     // [N/2] exchange buf A
  ull*      kx1u     = reinterpret_cast<ull*>(W + 1024 + N); // [N/2] exchange buf B

  // ---- persistent LDS constants ----
  if (tid < ROWS)             r_sh[tid]   = r[rowbase + tid];
  if (tid < ROWS * PERTS)     eps_sh[tid] = eps[rowbase * PERTS + tid];
  if (tid < (Tm + 1) * PERTS) P_sh[tid]   = Pm[tid];
  if (tid < ROWS)             ysb_rows[tid] = x[rowbase + tid];

  // ---- A fragment -> registers (fp16), once ----
  // Thread owns cols (q*256+tid)*4..+3 (q=0..3) of rows rowbase..rowbase+15.
  __half2 Af[ROWS][8];
  #pragma unroll
  for (int rr = 0; rr < ROWS; rr++){
    const float* Ar = A + (size_t)(rowbase + rr) * N;
    #pragma unroll
    for (int q = 0; q < 4; q++){
      int c = (q * NTHR + tid) * 4;
      float4 a = ld4(Ar + c);
      Af[rr][2*q]   = __floats2half2_rn(a.x, a.y);
      Af[rr][2*q+1] = __floats2half2_rn(a.z, a.w);
    }
  }

  float4 ysbf[4], ysf[4];              // base / stage vector fragments (fp32)
  #pragma unroll
  for (int q = 0; q < 4; q++) ysbf[q] = ld4(x + (q * NTHR + tid) * 4);
  __syncthreads();

  const float t_end = (float)(*tptr);
  const float Tf    = (float)Tm;
  float t = 0.0f;
  float h = t_end * 0.01f;
  unsigned gen = 0;
  int pp = 0;                          // part_sm bank selector

  // matvec from registers: acc over our 16 cols, wave-reduce, park in part_sm.
  // Banks alternate per call -> no WAR vs previous stage's kval readers ->
  // the old leading __syncthreads is gone; the single barrier orders both
  // the partial writes and the preceding exchange epilogue's LDS writes.
  auto mv = [&](){
    pp ^= 1;
    float acc[ROWS];
    #pragma unroll
    for (int rr = 0; rr < ROWS; rr++) acc[rr] = 0.0f;
    #pragma unroll
    for (int q = 0; q < 4; q++){
      float4 y = ysf[q];
      #pragma unroll
      for (int rr = 0; rr < ROWS; rr++){
        float2 lo = __half22float2(Af[rr][2*q]);
        float2 hi = __half22float2(Af[rr][2*q+1]);
        acc[rr] = fmaf(lo.x, y.x, fmaf(lo.y, y.y, fmaf(hi.x, y.z, fmaf(hi.y, y.w, acc[rr]))));
      }
    }
    #pragma unroll
    for (int rr = 0; rr < ROWS; rr++){
      float s = acc[rr];
      #pragma unroll
      for (int off = 32; off; off >>= 1) s += __shfl_xor(s, off, 64);
      if (lane == 0) part_sm[pp][rr * 4 + wv] = s;
    }
    __syncthreads();
  };

  // k for row `tid` (tid<ROWS): y_s * (r + A@y_s + eps@P[d])
  auto kval = [&](float ts) -> float {
    int d = (int)((Tf * ts) / 30.0f);
    d = d < 0 ? 0 : (d > Tm ? Tm : d);
    const float* pb = part_sm[pp];
    float dot = pb[tid*4] + pb[tid*4+1] + pb[tid*4+2] + pb[tid*4+3];
    float ep = 0.f;
    #pragma unroll
    for (int p = 0; p < PERTS; p++) ep += eps_sh[tid * PERTS + p] * P_sh[d * PERTS + p];
    return ys_rows[tid] * (r_sh[tid] + dot + ep);
  };

  // classic build (stage-2 at loop head; depends on accept decision)
  auto build = [&](const int* sli, const float* cf, int nk){
    #pragma unroll
    for (int q = 0; q < 4; q++){
      int c = (q * NTHR + tid) * 4;
      float4 v = ysbf[q];
      for (int m = 0; m < nk; m++){
        float cc = h * cf[m];
        float4 kv = ld4(&khist[sli[m]][c]);
        v.x = fmaf(cc, kv.x, v.x); v.y = fmaf(cc, kv.y, v.y);
        v.z = fmaf(cc, kv.z, v.z); v.w = fmaf(cc, kv.w, v.w);
      }
      ysf[q] = v;
      int o = c - rowbase;             // c,rowbase multiples of 4/16: full containment
      if (o >= 0 && o < ROWS) st4(&ys_rows[o], v);
    }
    __syncthreads();
  };

  // FAST publish (stages 1-6): wave0 autonomously stores k, ACKs (wave-scoped
  // waitcnt), raises the flag -- no intra-block barrier; waves 1-3 pre-build.
  auto publish_fast = [&](float kv) -> ull* {
    ++gen;
    ull* kx = (gen & 1u) ? kx1u : kx0u;          // double buffer by parity
    if (wv == 0){
      float kvn = __shfl_down(kv, 1, 64);
      if ((lane & 1) == 0 && lane < ROWS){
        union { float2 f; ull u; } cv;
        cv.f = make_float2(kv, kvn);
        __hip_atomic_store(&kx[(rowbase >> 1) + (lane >> 1)], cv.u,
                           __ATOMIC_RELAXED, __HIP_MEMORY_SCOPE_AGENT);
      }
      __builtin_amdgcn_sched_barrier(0);
      __builtin_amdgcn_s_waitcnt(0);             // wave0's k stores at coherence point
      __builtin_amdgcn_sched_barrier(0);
      if (lane == 0)
        __hip_atomic_store(&flags[b], gen, __ATOMIC_RELAXED, __HIP_MEMORY_SCOPE_AGENT);
    }
    return kx;
  };

  // R7 publish (stage 7): barrier'd (epr_sh aggregation precedes errv anyway)
  auto publish_flag = [&](float kv, bool werr, float errv) -> ull* {
    ++gen;
    ull* kx = (gen & 1u) ? kx1u : kx0u;          // double buffer by parity
    if (wv == 0){
      float kvn = __shfl_down(kv, 1, 64);
      if ((lane & 1) == 0 && lane < ROWS){
        union { float2 f; ull u; } cv;
        cv.f = make_float2(kv, kvn);
        __hip_atomic_store(&kx[(rowbase >> 1) + (lane >> 1)], cv.u,
                           __ATOMIC_RELAXED, __HIP_MEMORY_SCOPE_AGENT);
      }
      if (werr && lane == 0)
        __hip_atomic_store(&err_part[b], errv, __ATOMIC_RELAXED, __HIP_MEMORY_SCOPE_AGENT);
    }
    __syncthreads();                             // all stage work done
    if (tid == 0){
      __builtin_amdgcn_sched_barrier(0);
      __builtin_amdgcn_s_waitcnt(0);             // kx/err stores at coherence point
      __builtin_amdgcn_sched_barrier(0);
      __hip_atomic_store(&flags[b], gen, __ATOMIC_RELAXED, __HIP_MEMORY_SCOPE_AGENT);
    }
    return kx;
  };

  // detect: block0 scans all flags, replicates the packed (gen,err) word to
  // 8 lines (all wave0 lanes hold es after the xor tree; lanes 0-7 store in
  // parallel). Follower b polls ONLY bword8[b&7] (<=32 readers/line).
  auto detect = [&](bool werr){
    if (b == 0){
      if (wv == 0){
        for (;;){
          bool ok = true;
          #pragma unroll
          for (int j = 0; j < 4; j++){
            unsigned f = __hip_atomic_load(&flags[j * 64 + lane],
                                           __ATOMIC_RELAXED, __HIP_MEMORY_SCOPE_AGENT);
            ok = ok && (f >= gen);
          }
          if (__all(ok)) break;
          __builtin_amdgcn_s_sleep(1);
        }
        float es = 0.f;
        if (werr){                               // R7 order -> bitwise identical
          #pragma unroll
          for (int j = 0; j < 4; j++)
            es += __hip_atomic_load(&err_part[lane + j * 64],
                                    __ATOMIC_RELAXED, __HIP_MEMORY_SCOPE_AGENT);
          #pragma unroll
          for (int off = 32; off; off >>= 1) es += __shfl_xor(es, off, 64);
        }
        if (werr && lane == 0) es_sh = es;
        ull pk = ((ull)gen << 32) | (ull)__float_as_uint(es);
        if (lane < 8)
          __hip_atomic_store(&bword8[lane], pk, __ATOMIC_RELAXED, __HIP_MEMORY_SCOPE_AGENT);
      }
      __syncthreads();
    } else {
      if (tid == 0){
        ull* myw = &bword8[b & 7];
        for (;;){
          ull w = __hip_atomic_load(myw, __ATOMIC_RELAXED, __HIP_MEMORY_SCOPE_AGENT);
          if ((unsigned)(w >> 32) >= gen){
            if (werr) es_sh = __uint_as_float((unsigned)(w & 0xffffffffu));
            break;
          }
          __builtin_amdgcn_s_sleep(1);
        }
      }
      __syncthreads();
    }
  };

  // classic exchange (stage 7): publish, detect(+err), pull full k into LDS
  auto exchange = [&](int slot, float kv, bool werr, float errv){
    ull* kx = publish_flag(kv, werr, errv);
    detect(werr);
    float2* kh2 = reinterpret_cast<float2*>(&khist[slot][0]);
    #pragma unroll
    for (int i = 0; i < 8; i++){                 // coalesced dwordx2 atomic loads
      union { float2 f; ull u; } cv;
      cv.u = __hip_atomic_load(&kx[i * NTHR + tid], __ATOMIC_RELAXED, __HIP_MEMORY_SCOPE_AGENT);
      kh2[i * NTHR + tid] = cv.f;
    }
    __syncthreads();                             // khist[slot]/es_sh ready
  };

  // overlapped exchange (stages 1..6): fast publish (wave0 autonomous), all
  // waves pre-build NEXT stage's ys from OLD slots during flag/detect, then
  // consume the new k from registers (always the LAST coefficient ->
  // bitwise-same fma order), park it in khist[slot_in] off the critical path.
  auto exchange_build = [&](int slot_in, float kv,
                            const int* sli_old, const float* cf_old, int nk_old,
                            float cf_new){
    ull* kx = publish_fast(kv);
    #pragma unroll
    for (int q = 0; q < 4; q++){                 // partial: old slots (stable LDS)
      int c = (q * NTHR + tid) * 4;
      float4 v = ysbf[q];
      for (int m = 0; m < nk_old; m++){
        float cc = h * cf_old[m];
        float4 kvv = ld4(&khist[sli_old[m]][c]);
        v.x = fmaf(cc, kvv.x, v.x); v.y = fmaf(cc, kvv.y, v.y);
        v.z = fmaf(cc, kvv.z, v.z); v.w = fmaf(cc, kvv.w, v.w);
      }
      ysf[q] = v;
    }
    detect(false);
    const float cc = h * cf_new;
    #pragma unroll
    for (int q = 0; q < 4; q++){                 // pull OWN columns, fma from regs
      int c = (q * NTHR + tid) * 4;
      union { float2 f; ull u; } c0, c1;
      c0.u = __hip_atomic_load(&kx[(c >> 1)],     __ATOMIC_RELAXED, __HIP_MEMORY_SCOPE_AGENT);
      c1.u = __hip_atomic_load(&kx[(c >> 1) + 1], __ATOMIC_RELAXED, __HIP_MEMORY_SCOPE_AGENT);
      float4 v = ysf[q];
      v.x = fmaf(cc, c0.f.x, v.x); v.y = fmaf(cc, c0.f.y, v.y);
      v.z = fmaf(cc, c1.f.x, v.z); v.w = fmaf(cc, c1.f.y, v.w);
      ysf[q] = v;
      st4(&khist[slot_in][c], make_float4(c0.f.x, c0.f.y, c1.f.x, c1.f.y));
      int o = c - rowbase;
      if (o >= 0 && o < ROWS) st4(&ys_rows[o], v);
    }
    // no trailing __syncthreads: mv()'s barrier publishes khist/ys_rows
    // (slot_in is dead to every partial-build list in this step).
  };

  int sl[6] = {0, 1, 2, 3, 4, 5};      // logical k1..k6 -> physical LDS slots
  bool exhausted = true;

  for (int n = 0; n < MAXSTEP; ++n){
    if (n > 0){
      float es = es_sh;                          // set by last stage-7 exchange
      float enorm = sqrtf(es * (1.0f / (float)N));
      bool accept = (enorm <= 1.0f);
      if (accept){
        t += h;
        int tmp = sl[0]; sl[0] = sl[1]; sl[1] = tmp;  // FSAL: k1 <- k7 (in k2's slot)
        #pragma unroll
        for (int q = 0; q < 4; q++) ysbf[q] = ysf[q];
        if (tid < ROWS) ysb_rows[tid] = ys_rows[tid];
      }
      float fac = 0.9f * powf(enorm + 1e-10f, -0.2f);
      fac = fminf(fmaxf(fac, 0.2f), 10.0f);
      h *= fac;
      __syncthreads();
      if (t >= t_end) { exhausted = false; break; }
      h = fminf(h, t_end - t);
      if (!(h > 0.0f)) { exhausted = false; break; }
      // ---- stage-2 build (classic; depends on accept decision) ----
      { const float cf[1] = {0.2f}; const int s_[1] = {sl[0]};
        build(s_, cf, 1); }
    } else {
      if (t >= t_end) { exhausted = false; break; }
      h = fminf(h, t_end - t);
      if (!(h > 0.0f)) { exhausted = false; break; }
      // ---- stage 1 (once ever; FSAL covers later steps) ----
      #pragma unroll
      for (int q = 0; q < 4; q++){
        ysf[q] = ysbf[q];
        int c = (q * NTHR + tid) * 4, o = c - rowbase;
        if (o >= 0 && o < ROWS) st4(&ys_rows[o], ysf[q]);
      }
      __syncthreads();
      mv();
      float kv = (tid < ROWS) ? kval(t) : 0.f;
      exchange_build(sl[0], kv, nullptr, nullptr, 0, 0.2f);   // builds stage-2 ys
    }

    // ---- stage 2: publish k2, pre-build stage-3 ys ----
    mv();
    { float kv = (tid < ROWS) ? kval(t + 0.2f * h) : 0.f;
      const int s_[1] = {sl[0]}; const float cf[1] = {3.f/40.f};
      exchange_build(sl[1], kv, s_, cf, 1, 9.f/40.f); }

    // ---- stage 3: publish k3, pre-build stage-4 ys ----
    mv();
    { float kv = (tid < ROWS) ? kval(t + 0.3f * h) : 0.f;
      const int s_[2] = {sl[0], sl[1]}; const float cf[2] = {44.f/45.f, -56.f/15.f};
      exchange_build(sl[2], kv, s_, cf, 2, 32.f/9.f); }

    // ---- stage 4: publish k4, pre-build stage-5 ys ----
    mv();
    { float kv = (tid < ROWS) ? kval(t + 0.8f * h) : 0.f;
      const int s_[3] = {sl[0], sl[1], sl[2]};
      const float cf[3] = {19372.f/6561.f, -25360.f/2187.f, 64448.f/6561.f};
      exchange_build(sl[3], kv, s_, cf, 3, -212.f/729.f); }

    // ---- stage 5: publish k5, pre-build stage-6 ys ----
    mv();
    { float kv = (tid < ROWS) ? kval(t + (8.f/9.f) * h) : 0.f;
      const int s_[4] = {sl[0], sl[1], sl[2], sl[3]};
      const float cf[4] = {9017.f/3168.f, -355.f/33.f, 46732.f/5247.f, 49.f/176.f};
      exchange_build(sl[4], kv, s_, cf, 4, -5103.f/18656.f); }

    // ---- stage 6: publish k6, pre-build stage-7 ys (= y5 candidate) ----
    mv();
    { float kv = (tid < ROWS) ? kval(t + h) : 0.f;
      const int s_[4] = {sl[0], sl[2], sl[3], sl[4]};
      const float cf[4] = {35.f/384.f, 500.f/1113.f, 125.f/192.f, -2187.f/6784.f};
      exchange_build(sl[5], kv, s_, cf, 4, 11.f/84.f); }

    // ---- stage 7: err partial; classic exchange (k7 -> sl[1], k2 dead) ----
    mv();
    { float k7v = 0.f, errv = 0.f;
      if (tid < ROWS){
        k7v = kval(t + h);
        int gi = rowbase + tid;
        float e = (71.f/57600.f)  * khist[sl[0]][gi] - (71.f/16695.f)    * khist[sl[2]][gi]
                + (71.f/1920.f)   * khist[sl[3]][gi] - (17253.f/339200.f)* khist[sl[4]][gi]
                + (22.f/525.f)    * khist[sl[5]][gi] - (1.f/40.f)        * k7v;
        e *= h;
        float sc = 1e-6f + 1e-3f * fmaxf(fabsf(ysb_rows[tid]), fabsf(ys_rows[tid]));
        float q = e / sc;
        epr_sh[tid] = q * q;
      }
      __syncthreads();
      if (tid == 0){
        float s = 0.f;
        #pragma unroll
        for (int i = 0; i < ROWS; i++) s += epr_sh[i];
        errv = s;
      }
      exchange(sl[1], k7v, true, errv); }        // barrier + err broadcast + k7 fetch
  }

  if (exhausted){
    // apply the final (iteration 511) accept decision, as the reference does
    float es = es_sh;
    bool accept = sqrtf(es * (1.0f / (float)N)) <= 1.0f;
    if (tid < ROWS) out[rowbase + tid] = accept ? ys_rows[tid] : ysb_rows[tid];
  } else {
    if (tid < ROWS) out[rowbase + tid] = ysb_rows[tid];
  }
}

extern "C" void kernel_launch(void* const* d_in, const int* in_sizes, int n_in,
                              void* d_out, int out_size, void* d_ws, size_t ws_size,
                              hipStream_t stream)
{
  const float* x   = (const float*)d_in[0];
  const int*   tp  = (const int*)  d_in[1];
  const float* r   = (const float*)d_in[2];
  const float* A   = (const float*)d_in[3];
  const float* eps = (const float*)d_in[4];
  const float* Pm  = (const float*)d_in[5];
  float* out = (float*)d_out;
  float* W   = (float*)d_ws;
  int Tm = in_sizes[5] / PERTS - 1;   // P rows - 1  (== 30)

  // zero flags / err partials / replicated broadcast words (ws re-poisoned per call)
  hipMemsetAsync(d_ws, 0, 4096, stream);
  mbpert_rk45_kernel<<<dim3(NBLK), dim3(NTHR), 0, stream>>>(
      x, tp, r, A, eps, Pm, out, W, Tm);
}

// Round 11
// 11118.576 us; speedup vs baseline: 1.3135x; 1.1024x over previous
//
#include <hip/hip_runtime.h>
#include <hip/hip_fp16.h>
#include <math.h>

// Persistent RK45 (Dormand-Prince, FSAL) integrator for
//   dy/dt = y * (r + A@y + eps@P[d(t)]),  n=4096, up to 512 adaptive steps.
// R18 = R17 (11.80ms steady, best) + micro-pack, all parts individually proven:
//  (a) dwordx4 sc0 sc1 pulls (R12-proven bitwise): exchange_build 8x8B atomic
//      -> 4x16B; stage-7 pull likewise. Half the load issues, one vmcnt.
//  (b) stage-7 epr_sh barrier dropped: writers (tid 0-15) and reader (tid 0)
//      are all wave0 -> same-wave LDS ordering suffices.
//  (c) follower bword poll drops s_sleep (RT-bound anyway; kills quantization).
// Ledger (us/stage): R7 4.34 | R8 tagged 4.37 | R12 flat 4.55 | R13 counter
//   4.87 | R14 3.96 | R15 tagged+ovl 4.75 | R16 3.91 | R17 3.84.
// LAWS: <=1 wave/block polls <=few words (R8/R12/R15); no cached pulls (R11);
//   256-thr blocks only (R9/R10: 512-thr caps VGPR at 128 -> Af spills).
// Decomposition @R17: serial floor ~2.1-2.4us; rest = max-of-256 skew at
//   3072 barriers (not code-addressable; dataflow de-amplification measured
//   worse twice). This round targets the last addressable legs.
// A stays permanently in registers as fp16 (zero steady-state HBM traffic).

#define N        4096
#define NBLK     256
#define NTHR     256
#define ROWS     16          // rows of A per block (NBLK*ROWS == N)
#define MAXSTEP  512
#define PERTS    8

typedef unsigned long long ull;

static_assert(NBLK * ROWS == N, "row partition");
static_assert(NTHR * 16 == N, "column partition (4 float4 per thread)");

__device__ __forceinline__ float4 ld4(const float* p){ return *reinterpret_cast<const float4*>(p); }
__device__ __forceinline__ void   st4(float* p, float4 v){ *reinterpret_cast<float4*>(p) = v; }

__global__ void __launch_bounds__(NTHR, 1)
mbpert_rk45_kernel(const float* __restrict__ x, const int* __restrict__ tptr,
                   const float* __restrict__ r, const float* __restrict__ A,
                   const float* __restrict__ eps, const float* __restrict__ Pm,
                   float* __restrict__ out, float* __restrict__ W, int Tm)
{
  __shared__ float khist[6][N];        // 96 KB k-history (gfx950: 160KB LDS/WG)
  __shared__ float part_sm[2][ROWS * 4];  // double-buffered per-wave matvec partials
  __shared__ float ys_rows[ROWS];      // stage vector at our 16 row indices
  __shared__ float ysb_rows[ROWS];     // base vector at our 16 row indices
  __shared__ float r_sh[ROWS];
  __shared__ float eps_sh[ROWS * PERTS];
  __shared__ float P_sh[32 * PERTS];
  __shared__ float epr_sh[ROWS];
  __shared__ float es_sh;

  const int tid = threadIdx.x;
  const int b   = blockIdx.x;
  const int rowbase = b * ROWS;
  const int lane = tid & 63;
  const int wv   = tid >> 6;

  unsigned* flags    = reinterpret_cast<unsigned*>(W);       // [256] per-block stage flags
  float*    err_part = W + 256;                              // [256] err partials
  ull*      bword8   = reinterpret_cast<ull*>(W + 512);      // [8] replicated (gen<<32|err)
  ull*      kx0u     = reinterpret_cast<ull*>(W + 1024);     // [N/2] exchange buf A
  ull*      kx1u     = reinterpret_cast<ull*>(W + 1024 + N); // [N/2] exchange buf B

  // ---- persistent LDS constants ----
  if (tid < ROWS)             r_sh[tid]   = r[rowbase + tid];
  if (tid < ROWS * PERTS)     eps_sh[tid] = eps[rowbase * PERTS + tid];
  if (tid < (Tm + 1) * PERTS) P_sh[tid]   = Pm[tid];
  if (tid < ROWS)             ysb_rows[tid] = x[rowbase + tid];

  // ---- A fragment -> registers (fp16), once ----
  // Thread owns cols (q*256+tid)*4..+3 (q=0..3) of rows rowbase..rowbase+15.
  __half2 Af[ROWS][8];
  #pragma unroll
  for (int rr = 0; rr < ROWS; rr++){
    const float* Ar = A + (size_t)(rowbase + rr) * N;
    #pragma unroll
    for (int q = 0; q < 4; q++){
      int c = (q * NTHR + tid) * 4;
      float4 a = ld4(Ar + c);
      Af[rr][2*q]   = __floats2half2_rn(a.x, a.y);
      Af[rr][2*q+1] = __floats2half2_rn(a.z, a.w);
    }
  }

  float4 ysbf[4], ysf[4];              // base / stage vector fragments (fp32)
  #pragma unroll
  for (int q = 0; q < 4; q++) ysbf[q] = ld4(x + (q * NTHR + tid) * 4);
  __syncthreads();

  const float t_end = (float)(*tptr);
  const float Tf    = (float)Tm;
  float t = 0.0f;
  float h = t_end * 0.01f;
  unsigned gen = 0;
  int pp = 0;                          // part_sm bank selector

  // matvec from registers; banks alternate -> no leading barrier needed
  auto mv = [&](){
    pp ^= 1;
    float acc[ROWS];
    #pragma unroll
    for (int rr = 0; rr < ROWS; rr++) acc[rr] = 0.0f;
    #pragma unroll
    for (int q = 0; q < 4; q++){
      float4 y = ysf[q];
      #pragma unroll
      for (int rr = 0; rr < ROWS; rr++){
        float2 lo = __half22float2(Af[rr][2*q]);
        float2 hi = __half22float2(Af[rr][2*q+1]);
        acc[rr] = fmaf(lo.x, y.x, fmaf(lo.y, y.y, fmaf(hi.x, y.z, fmaf(hi.y, y.w, acc[rr]))));
      }
    }
    #pragma unroll
    for (int rr = 0; rr < ROWS; rr++){
      float s = acc[rr];
      #pragma unroll
      for (int off = 32; off; off >>= 1) s += __shfl_xor(s, off, 64);
      if (lane == 0) part_sm[pp][rr * 4 + wv] = s;
    }
    __syncthreads();
  };

  // k for row `tid` (tid<ROWS): y_s * (r + A@y_s + eps@P[d])
  auto kval = [&](float ts) -> float {
    int d = (int)((Tf * ts) / 30.0f);
    d = d < 0 ? 0 : (d > Tm ? Tm : d);
    const float* pb = part_sm[pp];
    float dot = pb[tid*4] + pb[tid*4+1] + pb[tid*4+2] + pb[tid*4+3];
    float ep = 0.f;
    #pragma unroll
    for (int p = 0; p < PERTS; p++) ep += eps_sh[tid * PERTS + p] * P_sh[d * PERTS + p];
    return ys_rows[tid] * (r_sh[tid] + dot + ep);
  };

  // classic build (stage-2 at loop head; depends on accept decision)
  auto build = [&](const int* sli, const float* cf, int nk){
    #pragma unroll
    for (int q = 0; q < 4; q++){
      int c = (q * NTHR + tid) * 4;
      float4 v = ysbf[q];
      for (int m = 0; m < nk; m++){
        float cc = h * cf[m];
        float4 kv = ld4(&khist[sli[m]][c]);
        v.x = fmaf(cc, kv.x, v.x); v.y = fmaf(cc, kv.y, v.y);
        v.z = fmaf(cc, kv.z, v.z); v.w = fmaf(cc, kv.w, v.w);
      }
      ysf[q] = v;
      int o = c - rowbase;             // c,rowbase multiples of 4/16: full containment
      if (o >= 0 && o < ROWS) st4(&ys_rows[o], v);
    }
    __syncthreads();
  };

  // wide uncached pull of all 4 own-column float4 chunks (R12-proven)
  auto pull4 = [&](ull* kx, float4& a0, float4& a1, float4& a2, float4& a3){
    const float4* src = reinterpret_cast<const float4*>(kx);
    asm volatile(
      "global_load_dwordx4 %0, %4, off sc0 sc1\n\t"
      "global_load_dwordx4 %1, %5, off sc0 sc1\n\t"
      "global_load_dwordx4 %2, %6, off sc0 sc1\n\t"
      "global_load_dwordx4 %3, %7, off sc0 sc1\n\t"
      "s_waitcnt vmcnt(0)"
      : "=&v"(a0), "=&v"(a1), "=&v"(a2), "=&v"(a3)
      : "v"(src + tid), "v"(src + 256 + tid), "v"(src + 512 + tid), "v"(src + 768 + tid)
      : "memory");
  };

  // FAST publish (stages 1-6): wave0 autonomously stores k, ACKs, flags.
  auto publish_fast = [&](float kv) -> ull* {
    ++gen;
    ull* kx = (gen & 1u) ? kx1u : kx0u;          // double buffer by parity
    if (wv == 0){
      float kvn = __shfl_down(kv, 1, 64);
      if ((lane & 1) == 0 && lane < ROWS){
        union { float2 f; ull u; } cv;
        cv.f = make_float2(kv, kvn);
        __hip_atomic_store(&kx[(rowbase >> 1) + (lane >> 1)], cv.u,
                           __ATOMIC_RELAXED, __HIP_MEMORY_SCOPE_AGENT);
      }
      __builtin_amdgcn_sched_barrier(0);
      __builtin_amdgcn_s_waitcnt(0);             // wave0's k stores at coherence point
      __builtin_amdgcn_sched_barrier(0);
      if (lane == 0)
        __hip_atomic_store(&flags[b], gen, __ATOMIC_RELAXED, __HIP_MEMORY_SCOPE_AGENT);
    }
    return kx;
  };

  // R7 publish (stage 7): barrier'd
  auto publish_flag = [&](float kv, bool werr, float errv) -> ull* {
    ++gen;
    ull* kx = (gen & 1u) ? kx1u : kx0u;          // double buffer by parity
    if (wv == 0){
      float kvn = __shfl_down(kv, 1, 64);
      if ((lane & 1) == 0 && lane < ROWS){
        union { float2 f; ull u; } cv;
        cv.f = make_float2(kv, kvn);
        __hip_atomic_store(&kx[(rowbase >> 1) + (lane >> 1)], cv.u,
                           __ATOMIC_RELAXED, __HIP_MEMORY_SCOPE_AGENT);
      }
      if (werr && lane == 0)
        __hip_atomic_store(&err_part[b], errv, __ATOMIC_RELAXED, __HIP_MEMORY_SCOPE_AGENT);
    }
    __syncthreads();                             // all stage work done
    if (tid == 0){
      __builtin_amdgcn_sched_barrier(0);
      __builtin_amdgcn_s_waitcnt(0);             // kx/err stores at coherence point
      __builtin_amdgcn_sched_barrier(0);
      __hip_atomic_store(&flags[b], gen, __ATOMIC_RELAXED, __HIP_MEMORY_SCOPE_AGENT);
    }
    return kx;
  };

  // detect: block0 scans flags, replicates packed (gen,err) to 8 lines;
  // follower b polls bword8[b&7] with no sleep (RT-bound spin, 8 lines).
  auto detect = [&](bool werr){
    if (b == 0){
      if (wv == 0){
        for (;;){
          bool ok = true;
          #pragma unroll
          for (int j = 0; j < 4; j++){
            unsigned f = __hip_atomic_load(&flags[j * 64 + lane],
                                           __ATOMIC_RELAXED, __HIP_MEMORY_SCOPE_AGENT);
            ok = ok && (f >= gen);
          }
          if (__all(ok)) break;
          __builtin_amdgcn_s_sleep(1);
        }
        float es = 0.f;
        if (werr){                               // R7 order -> bitwise identical
          #pragma unroll
          for (int j = 0; j < 4; j++)
            es += __hip_atomic_load(&err_part[lane + j * 64],
                                    __ATOMIC_RELAXED, __HIP_MEMORY_SCOPE_AGENT);
          #pragma unroll
          for (int off = 32; off; off >>= 1) es += __shfl_xor(es, off, 64);
        }
        if (werr && lane == 0) es_sh = es;
        ull pk = ((ull)gen << 32) | (ull)__float_as_uint(es);
        if (lane < 8)
          __hip_atomic_store(&bword8[lane], pk, __ATOMIC_RELAXED, __HIP_MEMORY_SCOPE_AGENT);
      }
      __syncthreads();
    } else {
      if (tid == 0){
        ull* myw = &bword8[b & 7];
        for (;;){
          ull w = __hip_atomic_load(myw, __ATOMIC_RELAXED, __HIP_MEMORY_SCOPE_AGENT);
          if ((unsigned)(w >> 32) >= gen){
            if (werr) es_sh = __uint_as_float((unsigned)(w & 0xffffffffu));
            break;
          }
        }
      }
      __syncthreads();
    }
  };

  // classic exchange (stage 7): publish, detect(+err), wide pull into LDS
  auto exchange = [&](int slot, float kv, bool werr, float errv){
    ull* kx = publish_flag(kv, werr, errv);
    detect(werr);
    float4 a0, a1, a2, a3;
    pull4(kx, a0, a1, a2, a3);
    float4* kh4 = reinterpret_cast<float4*>(&khist[slot][0]);
    kh4[tid]       = a0;
    kh4[256 + tid] = a1;
    kh4[512 + tid] = a2;
    kh4[768 + tid] = a3;
    __syncthreads();                             // khist[slot]/es_sh ready
  };

  // overlapped exchange (stages 1..6): fast publish, pre-build from OLD
  // slots during flag/detect, wide pull, register-consume the new k (always
  // the LAST coefficient -> bitwise-same fma order), park in khist[slot_in].
  auto exchange_build = [&](int slot_in, float kv,
                            const int* sli_old, const float* cf_old, int nk_old,
                            float cf_new){
    ull* kx = publish_fast(kv);
    #pragma unroll
    for (int q = 0; q < 4; q++){                 // partial: old slots (stable LDS)
      int c = (q * NTHR + tid) * 4;
      float4 v = ysbf[q];
      for (int m = 0; m < nk_old; m++){
        float cc = h * cf_old[m];
        float4 kvv = ld4(&khist[sli_old[m]][c]);
        v.x = fmaf(cc, kvv.x, v.x); v.y = fmaf(cc, kvv.y, v.y);
        v.z = fmaf(cc, kvv.z, v.z); v.w = fmaf(cc, kvv.w, v.w);
      }
      ysf[q] = v;
    }
    detect(false);
    float4 a[4];
    pull4(kx, a[0], a[1], a[2], a[3]);
    const float cc = h * cf_new;
    #pragma unroll
    for (int q = 0; q < 4; q++){                 // consume from registers
      int c = (q * NTHR + tid) * 4;
      float4 v = ysf[q];
      v.x = fmaf(cc, a[q].x, v.x); v.y = fmaf(cc, a[q].y, v.y);
      v.z = fmaf(cc, a[q].z, v.z); v.w = fmaf(cc, a[q].w, v.w);
      ysf[q] = v;
      st4(&khist[slot_in][c], a[q]);
      int o = c - rowbase;
      if (o >= 0 && o < ROWS) st4(&ys_rows[o], v);
    }
    // no trailing __syncthreads: mv()'s barrier publishes khist/ys_rows
    // (slot_in is dead to every partial-build list in this step).
  };

  int sl[6] = {0, 1, 2, 3, 4, 5};      // logical k1..k6 -> physical LDS slots
  bool exhausted = true;

  for (int n = 0; n < MAXSTEP; ++n){
    if (n > 0){
      float es = es_sh;                          // set by last stage-7 exchange
      float enorm = sqrtf(es * (1.0f / (float)N));
      bool accept = (enorm <= 1.0f);
      if (accept){
        t += h;
        int tmp = sl[0]; sl[0] = sl[1]; sl[1] = tmp;  // FSAL: k1 <- k7 (in k2's slot)
        #pragma unroll
        for (int q = 0; q < 4; q++) ysbf[q] = ysf[q];
        if (tid < ROWS) ysb_rows[tid] = ys_rows[tid];
      }
      float fac = 0.9f * powf(enorm + 1e-10f, -0.2f);
      fac = fminf(fmaxf(fac, 0.2f), 10.0f);
      h *= fac;
      __syncthreads();
      if (t >= t_end) { exhausted = false; break; }
      h = fminf(h, t_end - t);
      if (!(h > 0.0f)) { exhausted = false; break; }
      // ---- stage-2 build (classic; depends on accept decision) ----
      { const float cf[1] = {0.2f}; const int s_[1] = {sl[0]};
        build(s_, cf, 1); }
    } else {
      if (t >= t_end) { exhausted = false; break; }
      h = fminf(h, t_end - t);
      if (!(h > 0.0f)) { exhausted = false; break; }
      // ---- stage 1 (once ever; FSAL covers later steps) ----
      #pragma unroll
      for (int q = 0; q < 4; q++){
        ysf[q] = ysbf[q];
        int c = (q * NTHR + tid) * 4, o = c - rowbase;
        if (o >= 0 && o < ROWS) st4(&ys_rows[o], ysf[q]);
      }
      __syncthreads();
      mv();
      float kv = (tid < ROWS) ? kval(t) : 0.f;
      exchange_build(sl[0], kv, nullptr, nullptr, 0, 0.2f);   // builds stage-2 ys
    }

    // ---- stage 2: publish k2, pre-build stage-3 ys ----
    mv();
    { float kv = (tid < ROWS) ? kval(t + 0.2f * h) : 0.f;
      const int s_[1] = {sl[0]}; const float cf[1] = {3.f/40.f};
      exchange_build(sl[1], kv, s_, cf, 1, 9.f/40.f); }

    // ---- stage 3: publish k3, pre-build stage-4 ys ----
    mv();
    { float kv = (tid < ROWS) ? kval(t + 0.3f * h) : 0.f;
      const int s_[2] = {sl[0], sl[1]}; const float cf[2] = {44.f/45.f, -56.f/15.f};
      exchange_build(sl[2], kv, s_, cf, 2, 32.f/9.f); }

    // ---- stage 4: publish k4, pre-build stage-5 ys ----
    mv();
    { float kv = (tid < ROWS) ? kval(t + 0.8f * h) : 0.f;
      const int s_[3] = {sl[0], sl[1], sl[2]};
      const float cf[3] = {19372.f/6561.f, -25360.f/2187.f, 64448.f/6561.f};
      exchange_build(sl[3], kv, s_, cf, 3, -212.f/729.f); }

    // ---- stage 5: publish k5, pre-build stage-6 ys ----
    mv();
    { float kv = (tid < ROWS) ? kval(t + (8.f/9.f) * h) : 0.f;
      const int s_[4] = {sl[0], sl[1], sl[2], sl[3]};
      const float cf[4] = {9017.f/3168.f, -355.f/33.f, 46732.f/5247.f, 49.f/176.f};
      exchange_build(sl[4], kv, s_, cf, 4, -5103.f/18656.f); }

    // ---- stage 6: publish k6, pre-build stage-7 ys (= y5 candidate) ----
    mv();
    { float kv = (tid < ROWS) ? kval(t + h) : 0.f;
      const int s_[4] = {sl[0], sl[2], sl[3], sl[4]};
      const float cf[4] = {35.f/384.f, 500.f/1113.f, 125.f/192.f, -2187.f/6784.f};
      exchange_build(sl[5], kv, s_, cf, 4, 11.f/84.f); }

    // ---- stage 7: err partial; classic exchange (k7 -> sl[1], k2 dead) ----
    mv();
    { float k7v = 0.f, errv = 0.f;
      if (tid < ROWS){
        k7v = kval(t + h);
        int gi = rowbase + tid;
        float e = (71.f/57600.f)  * khist[sl[0]][gi] - (71.f/16695.f)    * khist[sl[2]][gi]
                + (71.f/1920.f)   * khist[sl[3]][gi] - (17253.f/339200.f)* khist[sl[4]][gi]
                + (22.f/525.f)    * khist[sl[5]][gi] - (1.f/40.f)        * k7v;
        e *= h;
        float sc = 1e-6f + 1e-3f * fmaxf(fabsf(ysb_rows[tid]), fabsf(ys_rows[tid]));
        float q = e / sc;
        epr_sh[tid] = q * q;
      }
      // no barrier: epr_sh writers (tid 0-15) and reader (tid 0) are wave0;
      // same-wave LDS ordering suffices (publish_flag barriers the rest).
      if (tid == 0){
        float s = 0.f;
        #pragma unroll
        for (int i = 0; i < ROWS; i++) s += epr_sh[i];
        errv = s;
      }
      exchange(sl[1], k7v, true, errv); }        // barrier + err broadcast + k7 fetch
  }

  if (exhausted){
    // apply the final (iteration 511) accept decision, as the reference does
    float es = es_sh;
    bool accept = sqrtf(es * (1.0f / (float)N)) <= 1.0f;
    if (tid < ROWS) out[rowbase + tid] = accept ? ys_rows[tid] : ysb_rows[tid];
  } else {
    if (tid < ROWS) out[rowbase + tid] = ysb_rows[tid];
  }
}

extern "C" void kernel_launch(void* const* d_in, const int* in_sizes, int n_in,
                              void* d_out, int out_size, void* d_ws, size_t ws_size,
                              hipStream_t stream)
{
  const float* x   = (const float*)d_in[0];
  const int*   tp  = (const int*)  d_in[1];
  const float* r   = (const float*)d_in[2];
  const float* A   = (const float*)d_in[3];
  const float* eps = (const float*)d_in[4];
  const float* Pm  = (const float*)d_in[5];
  float* out = (float*)d_out;
  float* W   = (float*)d_ws;
  int Tm = in_sizes[5] / PERTS - 1;   // P rows - 1  (== 30)

  // zero flags / err partials / replicated broadcast words (ws re-poisoned per call)
  hipMemsetAsync(d_ws, 0, 4096, stream);
  mbpert_rk45_kernel<<<dim3(NBLK), dim3(NTHR), 0, stream>>>(
      x, tp, r, A, eps, Pm, out, W, Tm);
}

// Round 13
// 10664.756 us; speedup vs baseline: 1.3694x; 1.0426x over previous
//
#include <hip/hip_runtime.h>
#include <hip/hip_fp16.h>
#include <math.h>

// Persistent RK45 (Dormand-Prince, FSAL) integrator for
//   dy/dt = y * (r + A@y + eps@P[d(t)]),  n=4096, up to 512 adaptive steps.
// R19b = R18 (11.12ms, best) + stage-7 register consume ONLY.
//   R19 lesson: inline-asm global_store_dwordx4 cannot take a float4 INPUT
//   ("indirect register inputs" -- 128b tuples OK as asm outputs, not
//   inputs). Wide publish dropped; publish stays R18's 8x8B atomic stores.
//  (b) stage-7 register consume: exchange7 returns k7 in regs a7[4]; khist
//      park deferred (loop-head + mv barriers order it); loop head builds
//      stage-2 ys from regs (accept: k1=a7; reject: k1=old slot LDS) in the
//      exact old fma order. Drops 2 barriers + 1 LDS round trip per step.
// Ledger (us/stage): R7 4.34 | R13 4.87 | R14 3.96 | R15 4.75 | R16 3.91 |
//   R17 3.84 | R18 3.52. LAWS: <=1 wave/block polls <=few words (R8/R12/R15);
//   no cached pulls (R11); 256-thr blocks only (R9/R10: VGPR cap -> spill);
//   asm dwordx4 loads OK, asm dwordx4 stores don't compile (R19).
// A stays permanently in registers as fp16 (zero steady-state HBM traffic).

#define N        4096
#define NBLK     256
#define NTHR     256
#define ROWS     16          // rows of A per block (NBLK*ROWS == N)
#define MAXSTEP  512
#define PERTS    8

typedef unsigned long long ull;

static_assert(NBLK * ROWS == N, "row partition");
static_assert(NTHR * 16 == N, "column partition (4 float4 per thread)");

__device__ __forceinline__ float4 ld4(const float* p){ return *reinterpret_cast<const float4*>(p); }
__device__ __forceinline__ void   st4(float* p, float4 v){ *reinterpret_cast<float4*>(p) = v; }

__global__ void __launch_bounds__(NTHR, 1)
mbpert_rk45_kernel(const float* __restrict__ x, const int* __restrict__ tptr,
                   const float* __restrict__ r, const float* __restrict__ A,
                   const float* __restrict__ eps, const float* __restrict__ Pm,
                   float* __restrict__ out, float* __restrict__ W, int Tm)
{
  __shared__ float khist[6][N];        // 96 KB k-history (gfx950: 160KB LDS/WG)
  __shared__ float part_sm[2][ROWS * 4];  // double-buffered per-wave matvec partials
  __shared__ float ys_rows[ROWS];      // stage vector at our 16 row indices
  __shared__ float ysb_rows[ROWS];     // base vector at our 16 row indices
  __shared__ float r_sh[ROWS];
  __shared__ float eps_sh[ROWS * PERTS];
  __shared__ float P_sh[32 * PERTS];
  __shared__ float epr_sh[ROWS];
  __shared__ float es_sh;

  const int tid = threadIdx.x;
  const int b   = blockIdx.x;
  const int rowbase = b * ROWS;
  const int lane = tid & 63;
  const int wv   = tid >> 6;

  unsigned* flags    = reinterpret_cast<unsigned*>(W);       // [256] per-block stage flags
  float*    err_part = W + 256;                              // [256] err partials
  ull*      bword8   = reinterpret_cast<ull*>(W + 512);      // [8] replicated (gen<<32|err)
  ull*      kx0u     = reinterpret_cast<ull*>(W + 1024);     // [N/2] exchange buf A
  ull*      kx1u     = reinterpret_cast<ull*>(W + 1024 + N); // [N/2] exchange buf B

  // ---- persistent LDS constants ----
  if (tid < ROWS)             r_sh[tid]   = r[rowbase + tid];
  if (tid < ROWS * PERTS)     eps_sh[tid] = eps[rowbase * PERTS + tid];
  if (tid < (Tm + 1) * PERTS) P_sh[tid]   = Pm[tid];
  if (tid < ROWS)             ysb_rows[tid] = x[rowbase + tid];

  // ---- A fragment -> registers (fp16), once ----
  // Thread owns cols (q*256+tid)*4..+3 (q=0..3) of rows rowbase..rowbase+15.
  __half2 Af[ROWS][8];
  #pragma unroll
  for (int rr = 0; rr < ROWS; rr++){
    const float* Ar = A + (size_t)(rowbase + rr) * N;
    #pragma unroll
    for (int q = 0; q < 4; q++){
      int c = (q * NTHR + tid) * 4;
      float4 a = ld4(Ar + c);
      Af[rr][2*q]   = __floats2half2_rn(a.x, a.y);
      Af[rr][2*q+1] = __floats2half2_rn(a.z, a.w);
    }
  }

  float4 ysbf[4], ysf[4];              // base / stage vector fragments (fp32)
  #pragma unroll
  for (int q = 0; q < 4; q++) ysbf[q] = ld4(x + (q * NTHR + tid) * 4);
  __syncthreads();

  const float t_end = (float)(*tptr);
  const float Tf    = (float)Tm;
  float t = 0.0f;
  float h = t_end * 0.01f;
  unsigned gen = 0;
  int pp = 0;                          // part_sm bank selector

  // matvec from registers; banks alternate -> no leading barrier needed
  auto mv = [&](){
    pp ^= 1;
    float acc[ROWS];
    #pragma unroll
    for (int rr = 0; rr < ROWS; rr++) acc[rr] = 0.0f;
    #pragma unroll
    for (int q = 0; q < 4; q++){
      float4 y = ysf[q];
      #pragma unroll
      for (int rr = 0; rr < ROWS; rr++){
        float2 lo = __half22float2(Af[rr][2*q]);
        float2 hi = __half22float2(Af[rr][2*q+1]);
        acc[rr] = fmaf(lo.x, y.x, fmaf(lo.y, y.y, fmaf(hi.x, y.z, fmaf(hi.y, y.w, acc[rr]))));
      }
    }
    #pragma unroll
    for (int rr = 0; rr < ROWS; rr++){
      float s = acc[rr];
      #pragma unroll
      for (int off = 32; off; off >>= 1) s += __shfl_xor(s, off, 64);
      if (lane == 0) part_sm[pp][rr * 4 + wv] = s;
    }
    __syncthreads();
  };

  // k for row `tid` (tid<ROWS): y_s * (r + A@y_s + eps@P[d])
  auto kval = [&](float ts) -> float {
    int d = (int)((Tf * ts) / 30.0f);
    d = d < 0 ? 0 : (d > Tm ? Tm : d);
    const float* pb = part_sm[pp];
    float dot = pb[tid*4] + pb[tid*4+1] + pb[tid*4+2] + pb[tid*4+3];
    float ep = 0.f;
    #pragma unroll
    for (int p = 0; p < PERTS; p++) ep += eps_sh[tid * PERTS + p] * P_sh[d * PERTS + p];
    return ys_rows[tid] * (r_sh[tid] + dot + ep);
  };

  // wide uncached pull of all 4 own-column float4 chunks (R12-proven)
  auto pull4 = [&](ull* kx, float4& a0, float4& a1, float4& a2, float4& a3){
    const float4* src = reinterpret_cast<const float4*>(kx);
    asm volatile(
      "global_load_dwordx4 %0, %4, off sc0 sc1\n\t"
      "global_load_dwordx4 %1, %5, off sc0 sc1\n\t"
      "global_load_dwordx4 %2, %6, off sc0 sc1\n\t"
      "global_load_dwordx4 %3, %7, off sc0 sc1\n\t"
      "s_waitcnt vmcnt(0)"
      : "=&v"(a0), "=&v"(a1), "=&v"(a2), "=&v"(a3)
      : "v"(src + tid), "v"(src + 256 + tid), "v"(src + 512 + tid), "v"(src + 768 + tid)
      : "memory");
  };

  // FAST publish (stages 1-6): wave0 autonomously stores k, ACKs, flags.
  auto publish_fast = [&](float kv) -> ull* {
    ++gen;
    ull* kx = (gen & 1u) ? kx1u : kx0u;          // double buffer by parity
    if (wv == 0){
      float kvn = __shfl_down(kv, 1, 64);
      if ((lane & 1) == 0 && lane < ROWS){
        union { float2 f; ull u; } cv;
        cv.f = make_float2(kv, kvn);
        __hip_atomic_store(&kx[(rowbase >> 1) + (lane >> 1)], cv.u,
                           __ATOMIC_RELAXED, __HIP_MEMORY_SCOPE_AGENT);
      }
      __builtin_amdgcn_sched_barrier(0);
      __builtin_amdgcn_s_waitcnt(0);             // wave0's k stores at coherence point
      __builtin_amdgcn_sched_barrier(0);
      if (lane == 0)
        __hip_atomic_store(&flags[b], gen, __ATOMIC_RELAXED, __HIP_MEMORY_SCOPE_AGENT);
    }
    return kx;
  };

  // barrier'd publish (stage 7, +err)
  auto publish_flag = [&](float kv, float errv) -> ull* {
    ++gen;
    ull* kx = (gen & 1u) ? kx1u : kx0u;          // double buffer by parity
    if (wv == 0){
      float kvn = __shfl_down(kv, 1, 64);
      if ((lane & 1) == 0 && lane < ROWS){
        union { float2 f; ull u; } cv;
        cv.f = make_float2(kv, kvn);
        __hip_atomic_store(&kx[(rowbase >> 1) + (lane >> 1)], cv.u,
                           __ATOMIC_RELAXED, __HIP_MEMORY_SCOPE_AGENT);
      }
      if (lane == 0)
        __hip_atomic_store(&err_part[b], errv, __ATOMIC_RELAXED, __HIP_MEMORY_SCOPE_AGENT);
    }
    __syncthreads();                             // all stage work done
    if (tid == 0){
      __builtin_amdgcn_sched_barrier(0);
      __builtin_amdgcn_s_waitcnt(0);             // kx/err stores at coherence point
      __builtin_amdgcn_sched_barrier(0);
      __hip_atomic_store(&flags[b], gen, __ATOMIC_RELAXED, __HIP_MEMORY_SCOPE_AGENT);
    }
    return kx;
  };

  // detect: block0 scans flags, replicates packed (gen,err) to 8 lines;
  // follower b polls bword8[b&7] (no sleep: RT-bound spin over 8 lines).
  auto detect = [&](bool werr){
    if (b == 0){
      if (wv == 0){
        for (;;){
          bool ok = true;
          #pragma unroll
          for (int j = 0; j < 4; j++){
            unsigned f = __hip_atomic_load(&flags[j * 64 + lane],
                                           __ATOMIC_RELAXED, __HIP_MEMORY_SCOPE_AGENT);
            ok = ok && (f >= gen);
          }
          if (__all(ok)) break;
          __builtin_amdgcn_s_sleep(1);
        }
        float es = 0.f;
        if (werr){                               // R7 order -> bitwise identical
          #pragma unroll
          for (int j = 0; j < 4; j++)
            es += __hip_atomic_load(&err_part[lane + j * 64],
                                    __ATOMIC_RELAXED, __HIP_MEMORY_SCOPE_AGENT);
          #pragma unroll
          for (int off = 32; off; off >>= 1) es += __shfl_xor(es, off, 64);
        }
        if (werr && lane == 0) es_sh = es;
        ull pk = ((ull)gen << 32) | (ull)__float_as_uint(es);
        if (lane < 8)
          __hip_atomic_store(&bword8[lane], pk, __ATOMIC_RELAXED, __HIP_MEMORY_SCOPE_AGENT);
      }
      __syncthreads();
    } else {
      if (tid == 0){
        ull* myw = &bword8[b & 7];
        for (;;){
          ull w = __hip_atomic_load(myw, __ATOMIC_RELAXED, __HIP_MEMORY_SCOPE_AGENT);
          if ((unsigned)(w >> 32) >= gen){
            if (werr) es_sh = __uint_as_float((unsigned)(w & 0xffffffffu));
            break;
          }
        }
      }
      __syncthreads();
    }
  };

  // stage-7 exchange: publish(+err), detect(+es), pull k7 into regs a[4];
  // khist[slot] LDS park deferred (loop-head + mv barriers order it;
  // first reader is stage-2's partial AFTER mv's barrier).
  auto exchange7 = [&](int slot, float kv, float errv, float4 (&a)[4]){
    ull* kx = publish_flag(kv, errv);
    detect(true);                                // barrier inside publishes es_sh
    pull4(kx, a[0], a[1], a[2], a[3]);
    float4* kh4 = reinterpret_cast<float4*>(&khist[slot][0]);
    kh4[tid]       = a[0];
    kh4[256 + tid] = a[1];
    kh4[512 + tid] = a[2];
    kh4[768 + tid] = a[3];
    // no trailing barrier (deferred to loop-head __syncthreads)
  };

  // overlapped exchange (stages 1..6): fast publish, pre-build from OLD
  // slots during flag/detect, wide pull, register-consume the new k (always
  // the LAST coefficient -> bitwise-same fma order), park in khist[slot_in].
  auto exchange_build = [&](int slot_in, float kv,
                            const int* sli_old, const float* cf_old, int nk_old,
                            float cf_new){
    ull* kx = publish_fast(kv);
    #pragma unroll
    for (int q = 0; q < 4; q++){                 // partial: old slots (stable LDS)
      int c = (q * NTHR + tid) * 4;
      float4 v = ysbf[q];
      for (int m = 0; m < nk_old; m++){
        float cc = h * cf_old[m];
        float4 kvv = ld4(&khist[sli_old[m]][c]);
        v.x = fmaf(cc, kvv.x, v.x); v.y = fmaf(cc, kvv.y, v.y);
        v.z = fmaf(cc, kvv.z, v.z); v.w = fmaf(cc, kvv.w, v.w);
      }
      ysf[q] = v;
    }
    detect(false);
    float4 a[4];
    pull4(kx, a[0], a[1], a[2], a[3]);
    const float cc = h * cf_new;
    #pragma unroll
    for (int q = 0; q < 4; q++){                 // consume from registers
      int c = (q * NTHR + tid) * 4;
      float4 v = ysf[q];
      v.x = fmaf(cc, a[q].x, v.x); v.y = fmaf(cc, a[q].y, v.y);
      v.z = fmaf(cc, a[q].z, v.z); v.w = fmaf(cc, a[q].w, v.w);
      ysf[q] = v;
      st4(&khist[slot_in][c], a[q]);
      int o = c - rowbase;
      if (o >= 0 && o < ROWS) st4(&ys_rows[o], v);
    }
    // no trailing __syncthreads: mv()'s barrier publishes khist/ys_rows
  };

  int sl[6] = {0, 1, 2, 3, 4, 5};      // logical k1..k6 -> physical LDS slots
  bool exhausted = true;
  float4 a7[4];                        // k7 regs carried stage7 -> next loop head

  for (int n = 0; n < MAXSTEP; ++n){
    if (n > 0){
      float es = es_sh;                          // published by exchange7's detect barrier
      float enorm = sqrtf(es * (1.0f / (float)N));
      bool accept = (enorm <= 1.0f);
      if (accept){
        t += h;
        int tmp = sl[0]; sl[0] = sl[1]; sl[1] = tmp;  // FSAL: k1 <- k7 (in k2's slot)
        #pragma unroll
        for (int q = 0; q < 4; q++) ysbf[q] = ysf[q];
        if (tid < ROWS) ysb_rows[tid] = ys_rows[tid];
      }
      float fac = 0.9f * powf(enorm + 1e-10f, -0.2f);
      fac = fminf(fmaxf(fac, 0.2f), 10.0f);
      h *= fac;
      __syncthreads();   // orders exchange7's khist park + ysb_rows/ys_rows
      if (t >= t_end) { exhausted = false; break; }
      h = fminf(h, t_end - t);
      if (!(h > 0.0f)) { exhausted = false; break; }
      // ---- stage-2 build from registers (accept: k1 = a7; reject: old k1 LDS)
      { const float cc = h * 0.2f;
        #pragma unroll
        for (int q = 0; q < 4; q++){
          int c = (q * NTHR + tid) * 4;
          float4 k1 = accept ? a7[q] : ld4(&khist[sl[0]][c]);
          float4 v = ysbf[q];
          v.x = fmaf(cc, k1.x, v.x); v.y = fmaf(cc, k1.y, v.y);
          v.z = fmaf(cc, k1.z, v.z); v.w = fmaf(cc, k1.w, v.w);
          ysf[q] = v;
          int o = c - rowbase;
          if (o >= 0 && o < ROWS) st4(&ys_rows[o], v);
        }
      }
      // no barrier: mv()'s trailing barrier orders ys_rows before kval reads
    } else {
      if (t >= t_end) { exhausted = false; break; }
      h = fminf(h, t_end - t);
      if (!(h > 0.0f)) { exhausted = false; break; }
      // ---- stage 1 (once ever; FSAL covers later steps) ----
      #pragma unroll
      for (int q = 0; q < 4; q++){
        ysf[q] = ysbf[q];
        int c = (q * NTHR + tid) * 4, o = c - rowbase;
        if (o >= 0 && o < ROWS) st4(&ys_rows[o], ysf[q]);
      }
      __syncthreads();
      mv();
      float kv = (tid < ROWS) ? kval(t) : 0.f;
      exchange_build(sl[0], kv, nullptr, nullptr, 0, 0.2f);   // builds stage-2 ys
    }

    // ---- stage 2: publish k2, pre-build stage-3 ys ----
    mv();
    { float kv = (tid < ROWS) ? kval(t + 0.2f * h) : 0.f;
      const int s_[1] = {sl[0]}; const float cf[1] = {3.f/40.f};
      exchange_build(sl[1], kv, s_, cf, 1, 9.f/40.f); }

    // ---- stage 3: publish k3, pre-build stage-4 ys ----
    mv();
    { float kv = (tid < ROWS) ? kval(t + 0.3f * h) : 0.f;
      const int s_[2] = {sl[0], sl[1]}; const float cf[2] = {44.f/45.f, -56.f/15.f};
      exchange_build(sl[2], kv, s_, cf, 2, 32.f/9.f); }

    // ---- stage 4: publish k4, pre-build stage-5 ys ----
    mv();
    { float kv = (tid < ROWS) ? kval(t + 0.8f * h) : 0.f;
      const int s_[3] = {sl[0], sl[1], sl[2]};
      const float cf[3] = {19372.f/6561.f, -25360.f/2187.f, 64448.f/6561.f};
      exchange_build(sl[3], kv, s_, cf, 3, -212.f/729.f); }

    // ---- stage 5: publish k5, pre-build stage-6 ys ----
    mv();
    { float kv = (tid < ROWS) ? kval(t + (8.f/9.f) * h) : 0.f;
      const int s_[4] = {sl[0], sl[1], sl[2], sl[3]};
      const float cf[4] = {9017.f/3168.f, -355.f/33.f, 46732.f/5247.f, 49.f/176.f};
      exchange_build(sl[4], kv, s_, cf, 4, -5103.f/18656.f); }

    // ---- stage 6: publish k6, pre-build stage-7 ys (= y5 candidate) ----
    mv();
    { float kv = (tid < ROWS) ? kval(t + h) : 0.f;
      const int s_[4] = {sl[0], sl[2], sl[3], sl[4]};
      const float cf[4] = {35.f/384.f, 500.f/1113.f, 125.f/192.f, -2187.f/6784.f};
      exchange_build(sl[5], kv, s_, cf, 4, 11.f/84.f); }

    // ---- stage 7: err partial; exchange7 (k7 -> sl[1] slot + regs a7) ----
    mv();
    { float k7v = 0.f, errv = 0.f;
      if (tid < ROWS){
        k7v = kval(t + h);
        int gi = rowbase + tid;
        float e = (71.f/57600.f)  * khist[sl[0]][gi] - (71.f/16695.f)    * khist[sl[2]][gi]
                + (71.f/1920.f)   * khist[sl[3]][gi] - (17253.f/339200.f)* khist[sl[4]][gi]
                + (22.f/525.f)    * khist[sl[5]][gi] - (1.f/40.f)        * k7v;
        e *= h;
        float sc = 1e-6f + 1e-3f * fmaxf(fabsf(ysb_rows[tid]), fabsf(ys_rows[tid]));
        float q = e / sc;
        epr_sh[tid] = q * q;
      }
      // no barrier: epr_sh writers (tid 0-15) and reader (tid 0) are wave0;
      // same-wave LDS ordering suffices (publish_flag barriers the rest).
      if (tid == 0){
        float s = 0.f;
        #pragma unroll
        for (int i = 0; i < ROWS; i++) s += epr_sh[i];
        errv = s;
      }
      exchange7(sl[1], k7v, errv, a7); }         // es barrier + k7 regs + LDS park
  }

  if (exhausted){
    // apply the final (iteration 511) accept decision, as the reference does
    float es = es_sh;
    bool accept = sqrtf(es * (1.0f / (float)N)) <= 1.0f;
    if (tid < ROWS) out[rowbase + tid] = accept ? ys_rows[tid] : ysb_rows[tid];
  } else {
    if (tid < ROWS) out[rowbase + tid] = ysb_rows[tid];
  }
}

extern "C" void kernel_launch(void* const* d_in, const int* in_sizes, int n_in,
                              void* d_out, int out_size, void* d_ws, size_t ws_size,
                              hipStream_t stream)
{
  const float* x   = (const float*)d_in[0];
  const int*   tp  = (const int*)  d_in[1];
  const float* r   = (const float*)d_in[2];
  const float* A   = (const float*)d_in[3];
  const float* eps = (const float*)d_in[4];
  const float* Pm  = (const float*)d_in[5];
  float* out = (float*)d_out;
  float* W   = (float*)d_ws;
  int Tm = in_sizes[5] / PERTS - 1;   // P rows - 1  (== 30)

  // zero flags / err partials / replicated broadcast words (ws re-poisoned per call)
  (void)hipMemsetAsync(d_ws, 0, 4096, stream);
  mbpert_rk45_kernel<<<dim3(NBLK), dim3(NTHR), 0, stream>>>(
      x, tp, r, A, eps, Pm, out, W, Tm);
}

// Round 14
// 10350.359 us; speedup vs baseline: 1.4110x; 1.0304x over previous
//
#include <hip/hip_runtime.h>
#include <hip/hip_fp16.h>
#include <math.h>

// Persistent RK45 (Dormand-Prince, FSAL) integrator for
//   dy/dt = y * (r + A@y + eps@P[d(t)]),  n=4096, up to 512 adaptive steps.
// R20 = R19b (10.66ms, best) + four relay-latency cuts (bitwise-neutral):
//  (1) scan-first for block0: aggregator wave scans flags IMMEDIATELY after
//      flag-raise; its pre-build moves behind the bword store (hidden under
//      follower catch). Pre-scan prebuild was ~0.1us on the GLOBAL chain.
//  (2) wide flag scan: one dwordx4 sc0 sc1 per lane covers all 256 flags
//      per sweep (1 issue+wait vs 4). Monotonic flags -> torn reads harmless.
//  (3) no s_sleep in the scan (1 wave, 1KB/sweep; kills catch quantization).
//  (4) bword8 -> bword64: xor-tree leaves es in ALL lanes; 64 replicated
//      words -> <=4 followers/line (was <=32).
// Ledger (us/stage): R7 4.34 | R13 4.87 | R14 3.96 | R15 4.75 | R16 3.91 |
//   R17 3.84 | R18 3.52 | R19b 3.45. LAWS: <=1 wave/block polls <=few words
//   (R8/R12/R15); no cached pulls (R11); 256-thr blocks only (R9/R10);
//   asm dwordx4 loads OK, dwordx4 stores don't compile (R19).
// A stays permanently in registers as fp16 (zero steady-state HBM traffic).

#define N        4096
#define NBLK     256
#define NTHR     256
#define ROWS     16          // rows of A per block (NBLK*ROWS == N)
#define MAXSTEP  512
#define PERTS    8

typedef unsigned long long ull;

static_assert(NBLK * ROWS == N, "row partition");
static_assert(NTHR * 16 == N, "column partition (4 float4 per thread)");

__device__ __forceinline__ float4 ld4(const float* p){ return *reinterpret_cast<const float4*>(p); }
__device__ __forceinline__ void   st4(float* p, float4 v){ *reinterpret_cast<float4*>(p) = v; }

__global__ void __launch_bounds__(NTHR, 1)
mbpert_rk45_kernel(const float* __restrict__ x, const int* __restrict__ tptr,
                   const float* __restrict__ r, const float* __restrict__ A,
                   const float* __restrict__ eps, const float* __restrict__ Pm,
                   float* __restrict__ out, float* __restrict__ W, int Tm)
{
  __shared__ float khist[6][N];        // 96 KB k-history (gfx950: 160KB LDS/WG)
  __shared__ float part_sm[2][ROWS * 4];  // double-buffered per-wave matvec partials
  __shared__ float ys_rows[ROWS];      // stage vector at our 16 row indices
  __shared__ float ysb_rows[ROWS];     // base vector at our 16 row indices
  __shared__ float r_sh[ROWS];
  __shared__ float eps_sh[ROWS * PERTS];
  __shared__ float P_sh[32 * PERTS];
  __shared__ float epr_sh[ROWS];
  __shared__ float es_sh;

  const int tid = threadIdx.x;
  const int b   = blockIdx.x;
  const int rowbase = b * ROWS;
  const int lane = tid & 63;
  const int wv   = tid >> 6;

  unsigned* flags    = reinterpret_cast<unsigned*>(W);       // [256] per-block stage flags
  float*    err_part = W + 256;                              // [256] err partials
  ull*      bword64  = reinterpret_cast<ull*>(W + 512);      // [64] replicated (gen<<32|err)
  ull*      kx0u     = reinterpret_cast<ull*>(W + 1024);     // [N/2] exchange buf A
  ull*      kx1u     = reinterpret_cast<ull*>(W + 1024 + N); // [N/2] exchange buf B

  // ---- persistent LDS constants ----
  if (tid < ROWS)             r_sh[tid]   = r[rowbase + tid];
  if (tid < ROWS * PERTS)     eps_sh[tid] = eps[rowbase * PERTS + tid];
  if (tid < (Tm + 1) * PERTS) P_sh[tid]   = Pm[tid];
  if (tid < ROWS)             ysb_rows[tid] = x[rowbase + tid];

  // ---- A fragment -> registers (fp16), once ----
  // Thread owns cols (q*256+tid)*4..+3 (q=0..3) of rows rowbase..rowbase+15.
  __half2 Af[ROWS][8];
  #pragma unroll
  for (int rr = 0; rr < ROWS; rr++){
    const float* Ar = A + (size_t)(rowbase + rr) * N;
    #pragma unroll
    for (int q = 0; q < 4; q++){
      int c = (q * NTHR + tid) * 4;
      float4 a = ld4(Ar + c);
      Af[rr][2*q]   = __floats2half2_rn(a.x, a.y);
      Af[rr][2*q+1] = __floats2half2_rn(a.z, a.w);
    }
  }

  float4 ysbf[4], ysf[4];              // base / stage vector fragments (fp32)
  #pragma unroll
  for (int q = 0; q < 4; q++) ysbf[q] = ld4(x + (q * NTHR + tid) * 4);
  __syncthreads();

  const float t_end = (float)(*tptr);
  const float Tf    = (float)Tm;
  float t = 0.0f;
  float h = t_end * 0.01f;
  unsigned gen = 0;
  int pp = 0;                          // part_sm bank selector

  // matvec from registers; banks alternate -> no leading barrier needed
  auto mv = [&](){
    pp ^= 1;
    float acc[ROWS];
    #pragma unroll
    for (int rr = 0; rr < ROWS; rr++) acc[rr] = 0.0f;
    #pragma unroll
    for (int q = 0; q < 4; q++){
      float4 y = ysf[q];
      #pragma unroll
      for (int rr = 0; rr < ROWS; rr++){
        float2 lo = __half22float2(Af[rr][2*q]);
        float2 hi = __half22float2(Af[rr][2*q+1]);
        acc[rr] = fmaf(lo.x, y.x, fmaf(lo.y, y.y, fmaf(hi.x, y.z, fmaf(hi.y, y.w, acc[rr]))));
      }
    }
    #pragma unroll
    for (int rr = 0; rr < ROWS; rr++){
      float s = acc[rr];
      #pragma unroll
      for (int off = 32; off; off >>= 1) s += __shfl_xor(s, off, 64);
      if (lane == 0) part_sm[pp][rr * 4 + wv] = s;
    }
    __syncthreads();
  };

  // k for row `tid` (tid<ROWS): y_s * (r + A@y_s + eps@P[d])
  auto kval = [&](float ts) -> float {
    int d = (int)((Tf * ts) / 30.0f);
    d = d < 0 ? 0 : (d > Tm ? Tm : d);
    const float* pb = part_sm[pp];
    float dot = pb[tid*4] + pb[tid*4+1] + pb[tid*4+2] + pb[tid*4+3];
    float ep = 0.f;
    #pragma unroll
    for (int p = 0; p < PERTS; p++) ep += eps_sh[tid * PERTS + p] * P_sh[d * PERTS + p];
    return ys_rows[tid] * (r_sh[tid] + dot + ep);
  };

  // wide uncached pull of all 4 own-column float4 chunks (R12-proven)
  auto pull4 = [&](ull* kx, float4& a0, float4& a1, float4& a2, float4& a3){
    const float4* src = reinterpret_cast<const float4*>(kx);
    asm volatile(
      "global_load_dwordx4 %0, %4, off sc0 sc1\n\t"
      "global_load_dwordx4 %1, %5, off sc0 sc1\n\t"
      "global_load_dwordx4 %2, %6, off sc0 sc1\n\t"
      "global_load_dwordx4 %3, %7, off sc0 sc1\n\t"
      "s_waitcnt vmcnt(0)"
      : "=&v"(a0), "=&v"(a1), "=&v"(a2), "=&v"(a3)
      : "v"(src + tid), "v"(src + 256 + tid), "v"(src + 512 + tid), "v"(src + 768 + tid)
      : "memory");
  };

  // FAST publish (stages 1-6): wave0 autonomously stores k, ACKs, flags.
  auto publish_fast = [&](float kv) -> ull* {
    ++gen;
    ull* kx = (gen & 1u) ? kx1u : kx0u;          // double buffer by parity
    if (wv == 0){
      float kvn = __shfl_down(kv, 1, 64);
      if ((lane & 1) == 0 && lane < ROWS){
        union { float2 f; ull u; } cv;
        cv.f = make_float2(kv, kvn);
        __hip_atomic_store(&kx[(rowbase >> 1) + (lane >> 1)], cv.u,
                           __ATOMIC_RELAXED, __HIP_MEMORY_SCOPE_AGENT);
      }
      __builtin_amdgcn_sched_barrier(0);
      __builtin_amdgcn_s_waitcnt(0);             // wave0's k stores at coherence point
      __builtin_amdgcn_sched_barrier(0);
      if (lane == 0)
        __hip_atomic_store(&flags[b], gen, __ATOMIC_RELAXED, __HIP_MEMORY_SCOPE_AGENT);
    }
    return kx;
  };

  // barrier'd publish (stage 7, +err)
  auto publish_flag = [&](float kv, float errv) -> ull* {
    ++gen;
    ull* kx = (gen & 1u) ? kx1u : kx0u;          // double buffer by parity
    if (wv == 0){
      float kvn = __shfl_down(kv, 1, 64);
      if ((lane & 1) == 0 && lane < ROWS){
        union { float2 f; ull u; } cv;
        cv.f = make_float2(kv, kvn);
        __hip_atomic_store(&kx[(rowbase >> 1) + (lane >> 1)], cv.u,
                           __ATOMIC_RELAXED, __HIP_MEMORY_SCOPE_AGENT);
      }
      if (lane == 0)
        __hip_atomic_store(&err_part[b], errv, __ATOMIC_RELAXED, __HIP_MEMORY_SCOPE_AGENT);
    }
    __syncthreads();                             // all stage work done
    if (tid == 0){
      __builtin_amdgcn_sched_barrier(0);
      __builtin_amdgcn_s_waitcnt(0);             // kx/err stores at coherence point
      __builtin_amdgcn_sched_barrier(0);
      __hip_atomic_store(&flags[b], gen, __ATOMIC_RELAXED, __HIP_MEMORY_SCOPE_AGENT);
    }
    return kx;
  };

  // block0 wave0: wide 1-load-per-lane flag scan (no sleep), err reduce,
  // 64-way bword replication. All lanes hold es after the xor butterfly.
  auto scan_bword = [&](bool werr){
    const uint4* fl4 = reinterpret_cast<const uint4*>(flags) + lane;
    for (;;){
      uint4 f;
      asm volatile("global_load_dwordx4 %0, %1, off sc0 sc1\n\ts_waitcnt vmcnt(0)"
                   : "=&v"(f) : "v"(fl4) : "memory");
      bool ok = (f.x >= gen) && (f.y >= gen) && (f.z >= gen) && (f.w >= gen);
      if (__all(ok)) break;
    }
    float es = 0.f;
    if (werr){                                   // R7 order -> bitwise identical
      #pragma unroll
      for (int j = 0; j < 4; j++)
        es += __hip_atomic_load(&err_part[lane + j * 64],
                                __ATOMIC_RELAXED, __HIP_MEMORY_SCOPE_AGENT);
      #pragma unroll
      for (int off = 32; off; off >>= 1) es += __shfl_xor(es, off, 64);
      if (lane == 0) es_sh = es;
    }
    ull pk = ((ull)gen << 32) | (ull)__float_as_uint(es);
    __hip_atomic_store(&bword64[lane], pk, __ATOMIC_RELAXED, __HIP_MEMORY_SCOPE_AGENT);
  };

  // follower tid0: poll own replicated word (<=4 followers/line), no sleep
  auto poll_bword = [&](bool werr){
    ull* myw = &bword64[b & 63];
    for (;;){
      ull w = __hip_atomic_load(myw, __ATOMIC_RELAXED, __HIP_MEMORY_SCOPE_AGENT);
      if ((unsigned)(w >> 32) >= gen){
        if (werr) es_sh = __uint_as_float((unsigned)(w & 0xffffffffu));
        break;
      }
    }
  };

  // stage-7 exchange: publish(+err), scan/poll, pull k7 into regs a[4];
  // khist[slot] LDS park deferred (loop-head barrier orders it).
  auto exchange7 = [&](int slot, float kv, float errv, float4 (&a)[4]){
    ull* kx = publish_flag(kv, errv);
    if (b == 0){
      if (wv == 0) scan_bword(true);
      __syncthreads();
    } else {
      if (tid == 0) poll_bword(true);
      __syncthreads();
    }
    pull4(kx, a[0], a[1], a[2], a[3]);
    float4* kh4 = reinterpret_cast<float4*>(&khist[slot][0]);
    kh4[tid]       = a[0];
    kh4[256 + tid] = a[1];
    kh4[512 + tid] = a[2];
    kh4[768 + tid] = a[3];
    // no trailing barrier (deferred to loop-head __syncthreads)
  };

  // overlapped exchange (stages 1..6): fast publish; block0's aggregator
  // wave SCANS FIRST (prebuild after bword store, hidden under follower
  // catch) while its waves 1-3 prebuild concurrently; followers prebuild
  // then poll. Then wide pull + register consume (new k always the LAST
  // coefficient -> bitwise-same fma order), park in khist[slot_in].
  auto exchange_build = [&](int slot_in, float kv,
                            const int* sli_old, const float* cf_old, int nk_old,
                            float cf_new){
    ull* kx = publish_fast(kv);
    auto prebuild = [&](){
      #pragma unroll
      for (int q = 0; q < 4; q++){               // partial: old slots (stable LDS)
        int c = (q * NTHR + tid) * 4;
        float4 v = ysbf[q];
        for (int m = 0; m < nk_old; m++){
          float cc = h * cf_old[m];
          float4 kvv = ld4(&khist[sli_old[m]][c]);
          v.x = fmaf(cc, kvv.x, v.x); v.y = fmaf(cc, kvv.y, v.y);
          v.z = fmaf(cc, kvv.z, v.z); v.w = fmaf(cc, kvv.w, v.w);
        }
        ysf[q] = v;
      }
    };
    if (b == 0){
      if (wv == 0){ scan_bword(false); prebuild(); }
      else        { prebuild(); }
      __syncthreads();                           // waves 1-3 wait for scan
    } else {
      prebuild();
      if (tid == 0) poll_bword(false);
      __syncthreads();
    }
    float4 a[4];
    pull4(kx, a[0], a[1], a[2], a[3]);
    const float cc = h * cf_new;
    #pragma unroll
    for (int q = 0; q < 4; q++){                 // consume from registers
      int c = (q * NTHR + tid) * 4;
      float4 v = ysf[q];
      v.x = fmaf(cc, a[q].x, v.x); v.y = fmaf(cc, a[q].y, v.y);
      v.z = fmaf(cc, a[q].z, v.z); v.w = fmaf(cc, a[q].w, v.w);
      ysf[q] = v;
      st4(&khist[slot_in][c], a[q]);
      int o = c - rowbase;
      if (o >= 0 && o < ROWS) st4(&ys_rows[o], v);
    }
    // no trailing __syncthreads: mv()'s barrier publishes khist/ys_rows
  };

  int sl[6] = {0, 1, 2, 3, 4, 5};      // logical k1..k6 -> physical LDS slots
  bool exhausted = true;
  float4 a7[4];                        // k7 regs carried stage7 -> next loop head

  for (int n = 0; n < MAXSTEP; ++n){
    if (n > 0){
      float es = es_sh;                          // published by exchange7's barrier
      float enorm = sqrtf(es * (1.0f / (float)N));
      bool accept = (enorm <= 1.0f);
      if (accept){
        t += h;
        int tmp = sl[0]; sl[0] = sl[1]; sl[1] = tmp;  // FSAL: k1 <- k7 (in k2's slot)
        #pragma unroll
        for (int q = 0; q < 4; q++) ysbf[q] = ysf[q];
        if (tid < ROWS) ysb_rows[tid] = ys_rows[tid];
      }
      float fac = 0.9f * powf(enorm + 1e-10f, -0.2f);
      fac = fminf(fmaxf(fac, 0.2f), 10.0f);
      h *= fac;
      __syncthreads();   // orders exchange7's khist park + ysb_rows/ys_rows
      if (t >= t_end) { exhausted = false; break; }
      h = fminf(h, t_end - t);
      if (!(h > 0.0f)) { exhausted = false; break; }
      // ---- stage-2 build from registers (accept: k1 = a7; reject: old k1 LDS)
      { const float cc = h * 0.2f;
        #pragma unroll
        for (int q = 0; q < 4; q++){
          int c = (q * NTHR + tid) * 4;
          float4 k1 = accept ? a7[q] : ld4(&khist[sl[0]][c]);
          float4 v = ysbf[q];
          v.x = fmaf(cc, k1.x, v.x); v.y = fmaf(cc, k1.y, v.y);
          v.z = fmaf(cc, k1.z, v.z); v.w = fmaf(cc, k1.w, v.w);
          ysf[q] = v;
          int o = c - rowbase;
          if (o >= 0 && o < ROWS) st4(&ys_rows[o], v);
        }
      }
      // no barrier: mv()'s trailing barrier orders ys_rows before kval reads
    } else {
      if (t >= t_end) { exhausted = false; break; }
      h = fminf(h, t_end - t);
      if (!(h > 0.0f)) { exhausted = false; break; }
      // ---- stage 1 (once ever; FSAL covers later steps) ----
      #pragma unroll
      for (int q = 0; q < 4; q++){
        ysf[q] = ysbf[q];
        int c = (q * NTHR + tid) * 4, o = c - rowbase;
        if (o >= 0 && o < ROWS) st4(&ys_rows[o], ysf[q]);
      }
      __syncthreads();
      mv();
      float kv = (tid < ROWS) ? kval(t) : 0.f;
      exchange_build(sl[0], kv, nullptr, nullptr, 0, 0.2f);   // builds stage-2 ys
    }

    // ---- stage 2: publish k2, pre-build stage-3 ys ----
    mv();
    { float kv = (tid < ROWS) ? kval(t + 0.2f * h) : 0.f;
      const int s_[1] = {sl[0]}; const float cf[1] = {3.f/40.f};
      exchange_build(sl[1], kv, s_, cf, 1, 9.f/40.f); }

    // ---- stage 3: publish k3, pre-build stage-4 ys ----
    mv();
    { float kv = (tid < ROWS) ? kval(t + 0.3f * h) : 0.f;
      const int s_[2] = {sl[0], sl[1]}; const float cf[2] = {44.f/45.f, -56.f/15.f};
      exchange_build(sl[2], kv, s_, cf, 2, 32.f/9.f); }

    // ---- stage 4: publish k4, pre-build stage-5 ys ----
    mv();
    { float kv = (tid < ROWS) ? kval(t + 0.8f * h) : 0.f;
      const int s_[3] = {sl[0], sl[1], sl[2]};
      const float cf[3] = {19372.f/6561.f, -25360.f/2187.f, 64448.f/6561.f};
      exchange_build(sl[3], kv, s_, cf, 3, -212.f/729.f); }

    // ---- stage 5: publish k5, pre-build stage-6 ys ----
    mv();
    { float kv = (tid < ROWS) ? kval(t + (8.f/9.f) * h) : 0.f;
      const int s_[4] = {sl[0], sl[1], sl[2], sl[3]};
      const float cf[4] = {9017.f/3168.f, -355.f/33.f, 46732.f/5247.f, 49.f/176.f};
      exchange_build(sl[4], kv, s_, cf, 4, -5103.f/18656.f); }

    // ---- stage 6: publish k6, pre-build stage-7 ys (= y5 candidate) ----
    mv();
    { float kv = (tid < ROWS) ? kval(t + h) : 0.f;
      const int s_[4] = {sl[0], sl[2], sl[3], sl[4]};
      const float cf[4] = {35.f/384.f, 500.f/1113.f, 125.f/192.f, -2187.f/6784.f};
      exchange_build(sl[5], kv, s_, cf, 4, 11.f/84.f); }

    // ---- stage 7: err partial; exchange7 (k7 -> sl[1] slot + regs a7) ----
    mv();
    { float k7v = 0.f, errv = 0.f;
      if (tid < ROWS){
        k7v = kval(t + h);
        int gi = rowbase + tid;
        float e = (71.f/57600.f)  * khist[sl[0]][gi] - (71.f/16695.f)    * khist[sl[2]][gi]
                + (71.f/1920.f)   * khist[sl[3]][gi] - (17253.f/339200.f)* khist[sl[4]][gi]
                + (22.f/525.f)    * khist[sl[5]][gi] - (1.f/40.f)        * k7v;
        e *= h;
        float sc = 1e-6f + 1e-3f * fmaxf(fabsf(ysb_rows[tid]), fabsf(ys_rows[tid]));
        float q = e / sc;
        epr_sh[tid] = q * q;
      }
      // no barrier: epr_sh writers (tid 0-15) and reader (tid 0) are wave0;
      // same-wave LDS ordering suffices (publish_flag barriers the rest).
      if (tid == 0){
        float s = 0.f;
        #pragma unroll
        for (int i = 0; i < ROWS; i++) s += epr_sh[i];
        errv = s;
      }
      exchange7(sl[1], k7v, errv, a7); }         // es barrier + k7 regs + LDS park
  }

  if (exhausted){
    // apply the final (iteration 511) accept decision, as the reference does
    float es = es_sh;
    bool accept = sqrtf(es * (1.0f / (float)N)) <= 1.0f;
    if (tid < ROWS) out[rowbase + tid] = accept ? ys_rows[tid] : ysb_rows[tid];
  } else {
    if (tid < ROWS) out[rowbase + tid] = ysb_rows[tid];
  }
}

extern "C" void kernel_launch(void* const* d_in, const int* in_sizes, int n_in,
                              void* d_out, int out_size, void* d_ws, size_t ws_size,
                              hipStream_t stream)
{
  const float* x   = (const float*)d_in[0];
  const int*   tp  = (const int*)  d_in[1];
  const float* r   = (const float*)d_in[2];
  const float* A   = (const float*)d_in[3];
  const float* eps = (const float*)d_in[4];
  const float* Pm  = (const float*)d_in[5];
  float* out = (float*)d_out;
  float* W   = (float*)d_ws;
  int Tm = in_sizes[5] / PERTS - 1;   // P rows - 1  (== 30)

  // zero flags / err partials / replicated broadcast words (ws re-poisoned per call)
  (void)hipMemsetAsync(d_ws, 0, 4096, stream);
  mbpert_rk45_kernel<<<dim3(NBLK), dim3(NTHR), 0, stream>>>(
      x, tp, r, A, eps, Pm, out, W, Tm);
}